// Round 2
// baseline (3949.389 us; speedup 1.0000x reference)
//
#include <hip/hip_runtime.h>
#include <math.h>

// Encoder block, fp32 baseline. B=8, T=1024, D=1024, H=16, dk=dv=64, FF=4096.
// softmax in reference is over the QUERY axis (axis=2 of (B,H,Tq,Ts)).
//
// Workspace budget (floats): 3 * M*D (Q,K,V) + 2 * B*H*T (stats) ~= 102 MB.
//   - attention output written straight to d_out (reused later as FF2 accum)
//   - o1 aliases K buffer (dead after attention)
//   - FF hidden computed in 4 chunks of 1024 into a 32MB scratch aliasing Q

#define B_ 8
#define T_ 1024
#define D_ 1024
#define H_ 16
#define DK_ 64
#define FF_ 4096
#define M_ (B_ * T_) // 8192

// ---------------------------------------------------------------------------
// Tiled fp32 GEMM: C[M,N] = A[M,K] @ B[K,N] (+ epilogue)
// BM=128, BN=64, BK=16, 256 threads, 8x4 per-thread micro-tile.
// BTRANS: B stored N x K row-major with row stride ldb (compute A @ B^T)
// BHEAD:  B is (H, D, 64) per-head blocks; col n -> head n>>6 (BN=64 tiles
//         stay within one head). ldb ignored.
// EPI: 0 none | 1 +res | 2 relu(+bias) | 3 +bias+res | 4 accumulate (C+=acc)
// ---------------------------------------------------------------------------
template <int EPI, bool BTRANS, bool BHEAD>
__global__ __launch_bounds__(256) void gemm_k(
    const float* __restrict__ A, const float* __restrict__ Bm,
    float* __restrict__ C, int M, int N, int K, int lda, int ldb, int ldc,
    const float* __restrict__ res, const float* __restrict__ bias) {
  __shared__ __align__(16) float As[16][132]; // A^T tile: As[k][m] (row = 528B, 16B-multiple)
  __shared__ __align__(16) float Bs[16][68];  // Bs[k][n] (row = 272B, 16B-multiple)

  const int tid = threadIdx.x;
  const int tx = tid & 15;      // 16 cols of 4
  const int ty = tid >> 4;      // 16 rows of 8
  const int m0 = blockIdx.y * 128;
  const int n0 = blockIdx.x * 64;

  const float* Bp = Bm + (BHEAD ? (size_t)(n0 >> 6) * (D_ * DK_) : (size_t)0);

  float acc[8][4];
#pragma unroll
  for (int i = 0; i < 8; ++i)
#pragma unroll
    for (int j = 0; j < 4; ++j) acc[i][j] = 0.f;

  const int arow = tid >> 2;     // 0..63
  const int ac4 = (tid & 3) * 4; // 0,4,8,12

  for (int k0 = 0; k0 < K; k0 += 16) {
    // A tile 128x16 -> As[k][m] (transposed in LDS)
#pragma unroll
    for (int l = 0; l < 2; ++l) {
      int row = arow + l * 64;
      float4 va = *(const float4*)&A[(size_t)(m0 + row) * lda + k0 + ac4];
      As[ac4 + 0][row] = va.x;
      As[ac4 + 1][row] = va.y;
      As[ac4 + 2][row] = va.z;
      As[ac4 + 3][row] = va.w;
    }
    // B tile 16x64
    if (!BTRANS) {
      int row = tid >> 4;      // 0..15 (k)
      int c4 = (tid & 15) * 4; // 0..60 (n)
      float4 vb = BHEAD ? *(const float4*)&Bp[(size_t)(k0 + row) * DK_ + c4]
                        : *(const float4*)&Bp[(size_t)(k0 + row) * ldb + n0 + c4];
      *(float4*)&Bs[row][c4] = vb;
    } else {
      int nr = tid >> 2;      // 0..63 (n)
      int c4 = (tid & 3) * 4; // 0..12 (k)
      float4 vb = *(const float4*)&Bp[(size_t)(n0 + nr) * ldb + k0 + c4];
      Bs[c4 + 0][nr] = vb.x;
      Bs[c4 + 1][nr] = vb.y;
      Bs[c4 + 2][nr] = vb.z;
      Bs[c4 + 3][nr] = vb.w;
    }
    __syncthreads();
#pragma unroll
    for (int kk = 0; kk < 16; ++kk) {
      float4 alo = *(const float4*)&As[kk][ty * 8];
      float4 ahi = *(const float4*)&As[kk][ty * 8 + 4];
      float4 bb = *(const float4*)&Bs[kk][tx * 4];
      float a[8] = {alo.x, alo.y, alo.z, alo.w, ahi.x, ahi.y, ahi.z, ahi.w};
      float bj[4] = {bb.x, bb.y, bb.z, bb.w};
#pragma unroll
      for (int i = 0; i < 8; ++i)
#pragma unroll
        for (int j = 0; j < 4; ++j) acc[i][j] += a[i] * bj[j];
    }
    __syncthreads();
  }

#pragma unroll
  for (int i = 0; i < 8; ++i) {
    int m = m0 + ty * 8 + i;
    int n = n0 + tx * 4;
    float4 prev;
    if (EPI == 4) prev = *(const float4*)&C[(size_t)m * ldc + n];
    float vj[4];
#pragma unroll
    for (int j = 0; j < 4; ++j) {
      float val = acc[i][j];
      if (EPI == 2 || EPI == 3) val += bias[n + j];
      if (EPI == 1 || EPI == 3) val += res[(size_t)m * ldc + n + j];
      if (EPI == 2) val = fmaxf(val, 0.f);
      if (EPI == 4) val += ((const float*)&prev)[j];
      vj[j] = val;
    }
    float4 o = {vj[0], vj[1], vj[2], vj[3]};
    *(float4*)&C[(size_t)m * ldc + n] = o;
  }
}

// ---------------------------------------------------------------------------
// Attention pass 1: per (b,h,s) column stats of S[q,s] = Q[q]·K[s]/8:
//   m[s] = max_q S,  l[s] = sum_q exp(S - m[s])
// Q/K layout: (b*T + t)*D + h*64 + k.  Block = (s-tile of 64, h, b).
// ---------------------------------------------------------------------------
__global__ __launch_bounds__(256) void attn_stats_k(
    const float* __restrict__ q, const float* __restrict__ k,
    float* __restrict__ Mbuf, float* __restrict__ Lbuf) {
  __shared__ __align__(16) float Ks[64][65];
  __shared__ __align__(16) float Qs[64][65];
  const int tid = threadIdx.x, tx = tid & 15, ty = tid >> 4;
  const int s0 = blockIdx.x * 64, h = blockIdx.y, b = blockIdx.z;
  const int bh = b * H_ + h;
  const float* kbase = k + (size_t)b * T_ * D_ + h * DK_;
  const float* qbase = q + (size_t)b * T_ * D_ + h * DK_;

  // K tile: 64 s-rows x 64 k-cols (fixed for the block)
#pragma unroll
  for (int l = 0; l < 4; ++l) {
    int idx = tid + l * 256;
    int row = idx >> 4, c4 = (idx & 15) * 4;
    float4 v = *(const float4*)&kbase[(size_t)(s0 + row) * D_ + c4];
    Ks[row][c4] = v.x; Ks[row][c4 + 1] = v.y;
    Ks[row][c4 + 2] = v.z; Ks[row][c4 + 3] = v.w;
  }

  float mrun[4], lrun[4];
#pragma unroll
  for (int i = 0; i < 4; ++i) { mrun[i] = -1e30f; lrun[i] = 0.f; }

  for (int q0 = 0; q0 < T_; q0 += 64) {
    __syncthreads(); // protect Qs (and Ks on first iter)
#pragma unroll
    for (int l = 0; l < 4; ++l) {
      int idx = tid + l * 256;
      int row = idx >> 4, c4 = (idx & 15) * 4;
      float4 v = *(const float4*)&qbase[(size_t)(q0 + row) * D_ + c4];
      Qs[row][c4] = v.x; Qs[row][c4 + 1] = v.y;
      Qs[row][c4 + 2] = v.z; Qs[row][c4 + 3] = v.w;
    }
    __syncthreads();

    float acc[4][4] = {};
#pragma unroll 4
    for (int kk = 0; kk < 64; ++kk) {
      float a[4], bq[4];
#pragma unroll
      for (int i = 0; i < 4; ++i) a[i] = Ks[ty * 4 + i][kk];
#pragma unroll
      for (int j = 0; j < 4; ++j) bq[j] = Qs[tx * 4 + j][kk];
#pragma unroll
      for (int i = 0; i < 4; ++i)
#pragma unroll
        for (int j = 0; j < 4; ++j) acc[i][j] += a[i] * bq[j];
    }
    // online stats per s-row (reduce over 16 tx lanes = q cols)
#pragma unroll
    for (int i = 0; i < 4; ++i) {
      float tmax = -1e30f;
#pragma unroll
      for (int j = 0; j < 4; ++j) tmax = fmaxf(tmax, acc[i][j] * 0.125f);
      for (int off = 1; off < 16; off <<= 1)
        tmax = fmaxf(tmax, __shfl_xor(tmax, off, 64));
      float nm = fmaxf(mrun[i], tmax);
      float ts = 0.f;
#pragma unroll
      for (int j = 0; j < 4; ++j) ts += expf(acc[i][j] * 0.125f - nm);
      for (int off = 1; off < 16; off <<= 1) ts += __shfl_xor(ts, off, 64);
      lrun[i] = lrun[i] * expf(mrun[i] - nm) + ts;
      mrun[i] = nm;
    }
  }
  if (tx == 0) {
#pragma unroll
    for (int i = 0; i < 4; ++i) {
      Mbuf[(size_t)bh * T_ + s0 + ty * 4 + i] = mrun[i];
      Lbuf[(size_t)bh * T_ + s0 + ty * 4 + i] = lrun[i];
    }
  }
}

// ---------------------------------------------------------------------------
// Attention pass 2: part[q,v] = sum_s exp(S[q,s]-m[s])/l[s] * V[s,v]
// Writes part in (b, t, h*64+v) layout (concat-heads done for free).
// ---------------------------------------------------------------------------
__global__ __launch_bounds__(256) void attn_apply_k(
    const float* __restrict__ q, const float* __restrict__ k,
    const float* __restrict__ v, const float* __restrict__ Mbuf,
    const float* __restrict__ Lbuf, float* __restrict__ part) {
  __shared__ __align__(16) float Qs[64][65];
  __shared__ __align__(16) float Ks[64][65];
  __shared__ __align__(16) float Vs[64][65];
  __shared__ __align__(16) float Ps[64][65];
  const int tid = threadIdx.x, tx = tid & 15, ty = tid >> 4;
  const int q0 = blockIdx.x * 64, h = blockIdx.y, b = blockIdx.z;
  const int bh = b * H_ + h;
  const float* qbase = q + (size_t)b * T_ * D_ + h * DK_;
  const float* kbase = k + (size_t)b * T_ * D_ + h * DK_;
  const float* vbase = v + (size_t)b * T_ * D_ + h * DK_;

  // Q tile fixed for the block
#pragma unroll
  for (int l = 0; l < 4; ++l) {
    int idx = tid + l * 256;
    int row = idx >> 4, c4 = (idx & 15) * 4;
    float4 vv = *(const float4*)&qbase[(size_t)(q0 + row) * D_ + c4];
    Qs[row][c4] = vv.x; Qs[row][c4 + 1] = vv.y;
    Qs[row][c4 + 2] = vv.z; Qs[row][c4 + 3] = vv.w;
  }

  float acc2[4][4] = {};
  for (int s0 = 0; s0 < T_; s0 += 64) {
    __syncthreads(); // protect Ks/Vs/Ps (and Qs first iter)
#pragma unroll
    for (int l = 0; l < 4; ++l) {
      int idx = tid + l * 256;
      int row = idx >> 4, c4 = (idx & 15) * 4;
      float4 vk = *(const float4*)&kbase[(size_t)(s0 + row) * D_ + c4];
      Ks[row][c4] = vk.x; Ks[row][c4 + 1] = vk.y;
      Ks[row][c4 + 2] = vk.z; Ks[row][c4 + 3] = vk.w;
      float4 vv = *(const float4*)&vbase[(size_t)(s0 + row) * D_ + c4];
      Vs[row][c4] = vv.x; Vs[row][c4 + 1] = vv.y;
      Vs[row][c4 + 2] = vv.z; Vs[row][c4 + 3] = vv.w;
    }
    __syncthreads();

    float ms[4], rl[4];
#pragma unroll
    for (int j = 0; j < 4; ++j) {
      ms[j] = Mbuf[(size_t)bh * T_ + s0 + tx * 4 + j];
      rl[j] = 1.f / Lbuf[(size_t)bh * T_ + s0 + tx * 4 + j];
    }

    float t[4][4] = {};
#pragma unroll 4
    for (int kk = 0; kk < 64; ++kk) {
      float a[4], bk[4];
#pragma unroll
      for (int i = 0; i < 4; ++i) a[i] = Qs[ty * 4 + i][kk];
#pragma unroll
      for (int j = 0; j < 4; ++j) bk[j] = Ks[tx * 4 + j][kk];
#pragma unroll
      for (int i = 0; i < 4; ++i)
#pragma unroll
        for (int j = 0; j < 4; ++j) t[i][j] += a[i] * bk[j];
    }
#pragma unroll
    for (int i = 0; i < 4; ++i)
#pragma unroll
      for (int j = 0; j < 4; ++j)
        Ps[ty * 4 + i][tx * 4 + j] = expf(t[i][j] * 0.125f - ms[j]) * rl[j];
    __syncthreads();

#pragma unroll 4
    for (int sl = 0; sl < 64; ++sl) {
      float a[4], bv[4];
#pragma unroll
      for (int i = 0; i < 4; ++i) a[i] = Ps[ty * 4 + i][sl];
#pragma unroll
      for (int j = 0; j < 4; ++j) bv[j] = Vs[sl][tx * 4 + j];
#pragma unroll
      for (int i = 0; i < 4; ++i)
#pragma unroll
        for (int j = 0; j < 4; ++j) acc2[i][j] += a[i] * bv[j];
    }
  }

#pragma unroll
  for (int i = 0; i < 4; ++i) {
    float4 w = {acc2[i][0], acc2[i][1], acc2[i][2], acc2[i][3]};
    *(float4*)&part[(size_t)(b * T_ + q0 + ty * 4 + i) * D_ + h * DK_ + tx * 4] = w;
  }
}

// ---------------------------------------------------------------------------
// Pseudo-norm: y - mean(y) - std(y, ddof=1), per row of 1024. One block/row.
// In-place safe (one block owns a row; reads before writes).
// ---------------------------------------------------------------------------
__global__ __launch_bounds__(256) void norm_k(const float* __restrict__ in,
                                              float* __restrict__ out) {
  __shared__ float red[8];
  const int row = blockIdx.x, tid = threadIdx.x;
  float4 vv = *(const float4*)&in[(size_t)row * D_ + tid * 4];
  float s = vv.x + vv.y + vv.z + vv.w;
  for (int off = 1; off < 64; off <<= 1) s += __shfl_xor(s, off, 64);
  if ((tid & 63) == 0) red[tid >> 6] = s;
  __syncthreads();
  float mean = (red[0] + red[1] + red[2] + red[3]) * (1.f / 1024.f);
  float dx = vv.x - mean, dy = vv.y - mean, dz = vv.z - mean, dw = vv.w - mean;
  float s2 = dx * dx + dy * dy + dz * dz + dw * dw;
  __syncthreads(); // red[] reuse
  for (int off = 1; off < 64; off <<= 1) s2 += __shfl_xor(s2, off, 64);
  if ((tid & 63) == 0) red[4 + (tid >> 6)] = s2;
  __syncthreads();
  float var = (red[4] + red[5] + red[6] + red[7]) * (1.f / 1023.f);
  float sd = sqrtf(var);
  float4 o = {dx - sd, dy - sd, dz - sd, dw - sd};
  *(float4*)&out[(size_t)row * D_ + tid * 4] = o;
}

// ---------------------------------------------------------------------------
extern "C" void kernel_launch(void* const* d_in, const int* in_sizes, int n_in,
                              void* d_out, int out_size, void* d_ws,
                              size_t ws_size, hipStream_t stream) {
  const float* x  = (const float*)d_in[0];
  const float* Wq = (const float*)d_in[1];
  const float* Wk = (const float*)d_in[2];
  const float* Wv = (const float*)d_in[3];
  const float* Wo = (const float*)d_in[4];
  const float* W1 = (const float*)d_in[5];
  const float* b1 = (const float*)d_in[6];
  const float* W2 = (const float*)d_in[7];
  const float* b2 = (const float*)d_in[8];
  float* out = (float*)d_out;

  const size_t Q = (size_t)M_ * D_; // 8,388,608 floats = 32 MB
  float* ws = (float*)d_ws;
  float* qb = ws;          // Q [later reused as FF hidden chunk]
  float* kb = qb + Q;      // Q [later reused as o1]
  float* vb = kb + Q;      // Q
  float* Mb = vb + Q;      // B*H*T
  float* Lb = Mb + (size_t)B_ * H_ * T_;
  // peak usage: 3*Q + 2*B*H*T floats ~= 102 MB

  float* part = out;       // attention output lives in d_out (32 MB)
  float* o1 = kb;          // aliases K buffer (dead after attention)
  float* hc = qb;          // FF hidden chunk aliases Q buffer (dead after attention)

  dim3 thr(256);
  dim3 gp(D_ / 64, M_ / 128);

  // QKV projections (per-head weight blocks via BHEAD)
  gemm_k<0, false, true><<<gp, thr, 0, stream>>>(x, Wq, qb, M_, D_, D_, D_, 0, D_, nullptr, nullptr);
  gemm_k<0, false, true><<<gp, thr, 0, stream>>>(x, Wk, kb, M_, D_, D_, D_, 0, D_, nullptr, nullptr);
  gemm_k<0, false, true><<<gp, thr, 0, stream>>>(x, Wv, vb, M_, D_, D_, D_, 0, D_, nullptr, nullptr);

  // attention with query-axis softmax (two-pass, no materialized scores)
  dim3 ga(T_ / 64, H_, B_);
  attn_stats_k<<<ga, thr, 0, stream>>>(qb, kb, Mb, Lb);
  attn_apply_k<<<ga, thr, 0, stream>>>(qb, kb, vb, Mb, Lb, part);

  // out1 = part @ Wo + x ; pseudo-norm in place (o1 overwrites kb)
  gemm_k<1, false, false><<<gp, thr, 0, stream>>>(part, Wo, o1, M_, D_, D_, D_, D_, D_, x, nullptr);
  norm_k<<<dim3(M_), thr, 0, stream>>>(o1, o1);

  // FF in 4 inner-dim chunks of 1024 (avoids 128MB hidden buffer):
  //   hc = relu(o1 @ W1_c^T + b1_c);  out (+)= hc @ W2_c^T  [+ b2 + o1 on c=0]
  for (int c = 0; c < 4; ++c) {
    const float* W1c = W1 + (size_t)c * 1024 * D_; // rows c*1024.. of (4096 x 1024)
    const float* b1c = b1 + (size_t)c * 1024;
    const float* W2c = W2 + (size_t)c * 1024;      // cols c*1024.. of (1024 x 4096)
    gemm_k<2, true, false><<<dim3(1024 / 64, M_ / 128), thr, 0, stream>>>(
        o1, W1c, hc, M_, 1024, D_, D_, D_, 1024, nullptr, b1c);
    if (c == 0) {
      gemm_k<3, true, false><<<gp, thr, 0, stream>>>(
          hc, W2c, part, M_, D_, 1024, 1024, FF_, D_, o1, b2);
    } else {
      gemm_k<4, true, false><<<gp, thr, 0, stream>>>(
          hc, W2c, part, M_, D_, 1024, 1024, FF_, D_, nullptr, nullptr);
    }
  }

  // final pseudo-norm in place on d_out
  norm_k<<<dim3(M_), thr, 0, stream>>>(part, out);
}

// Round 3
// 1650.806 us; speedup vs baseline: 2.3924x; 2.3924x over previous
//
#include <hip/hip_runtime.h>
#include <math.h>

// Encoder block. B=8, T=1024, D=1024, H=16, dk=dv=64, FF=4096.
// softmax in reference is over the QUERY axis (axis=2 of (B,H,Tq,Ts)).
//
// Round 3: all five GEMM groups moved to bf16 MFMA (m97 structure:
// 128x128 tile, BK=32, mfma_f32_16x16x32_bf16, global_load_lds 16B staging,
// fp32 accumulate + fp32 epilogues). Attention kernels kept fp32-compute but
// consume/produce bf16 tensors. Residuals, biases, softmax, norms all fp32.
//
// Workspace (~105 MB):
//  [0,16M)   qb16       [16,32M) kb16      [32,48M) vb16
//  [48,64M)  xb16  -> reused as o1b16 after QKV
//  [64,80M)  part16 -> reused as hc (FF1 chunk) after Wo GEMM
//  [80,86M)  Wqt/Wkt/Wvt   [86,88M) Wot   [88,96M) W1b   [96,104M) W2b
//  [104M..)  Mb, Lb (stats)
// o1 (fp32) lives in d_out; FF2 accumulates into d_out in place.

#define B_ 8
#define T_ 1024
#define D_ 1024
#define H_ 16
#define DK_ 64
#define FF_ 4096
#define M_ (B_ * T_) // 8192

typedef unsigned short u16;
typedef __attribute__((ext_vector_type(8))) short bf16x8;
typedef __attribute__((ext_vector_type(4))) float f32x4;

__device__ __forceinline__ float b2f(u16 u) {
  union { unsigned int i; float f; } x;
  x.i = ((unsigned int)u) << 16;
  return x.f;
}
__device__ __forceinline__ u16 f2b(float f) {
  union { float f; unsigned int i; } x;
  x.f = f;
  unsigned int r = (x.i + 0x7FFFu + ((x.i >> 16) & 1u)) >> 16; // RNE
  return (u16)r;
}

typedef __attribute__((address_space(1))) const void gas_void;
typedef __attribute__((address_space(3))) void las_void;
__device__ __forceinline__ void gload16(const void* g, void* l) {
  __builtin_amdgcn_global_load_lds((gas_void*)g, (las_void*)l, 16, 0, 0);
}

// ---------------------------------------------------------------------------
// bf16 MFMA GEMM, m97 structure. C[M,N] = A[M,K] @ Bt[N,K]^T
// A row-major (lda), Bt row-major N x K (ldb). 128x128 tile, BK=32,
// 256 threads = 4 waves, each wave owns a 64x64 quadrant (4x4 frags 16x16).
// EPI: 0: Cb=bf16(acc)            1: C=acc+res
//      2: Cb=bf16(relu(acc+bias)) 3: C=acc+bias+res   4: C+=acc
// ---------------------------------------------------------------------------
template <int EPI>
__global__ __launch_bounds__(256) void gemm16_k(
    const u16* __restrict__ A, const u16* __restrict__ Bt,
    int M, int N, int K, int lda, int ldb,
    float* __restrict__ C, int ldc, u16* __restrict__ Cb,
    const float* __restrict__ res, const float* __restrict__ bias) {
  __shared__ __align__(16) u16 As[128 * 32]; // [row m][k] linear, 8 KB
  __shared__ __align__(16) u16 Bs[128 * 32]; // [row n][k] linear, 8 KB

  const int tid = threadIdx.x;
  const int lane = tid & 63, wv = tid >> 6;
  const int m0 = blockIdx.y * 128, n0 = blockIdx.x * 128;
  const int wr = (wv >> 1) * 64, wc = (wv & 1) * 64;

  f32x4 acc[4][4];
#pragma unroll
  for (int i = 0; i < 4; ++i)
#pragma unroll
    for (int j = 0; j < 4; ++j) acc[i][j] = (f32x4){0.f, 0.f, 0.f, 0.f};

  // staging: row = wv*16 + lane/4 (+64 on issue 1), 8 elems at (lane&3)*8
  const int srow = wv * 16 + (lane >> 2);
  const int scol = (lane & 3) * 8;
  const int fr = lane & 15, fk = (lane >> 4) * 8;

  for (int k0 = 0; k0 < K; k0 += 32) {
    gload16(&A[(size_t)(m0 + srow) * lda + k0 + scol], &As[wv * 512]);
    gload16(&A[(size_t)(m0 + srow + 64) * lda + k0 + scol], &As[2048 + wv * 512]);
    gload16(&Bt[(size_t)(n0 + srow) * ldb + k0 + scol], &Bs[wv * 512]);
    gload16(&Bt[(size_t)(n0 + srow + 64) * ldb + k0 + scol], &Bs[2048 + wv * 512]);
    __syncthreads(); // compiler inserts vmcnt(0) drain

    bf16x8 af[4], bfr[4];
#pragma unroll
    for (int mi = 0; mi < 4; ++mi)
      af[mi] = *(const bf16x8*)&As[(wr + mi * 16 + fr) * 32 + fk];
#pragma unroll
    for (int ni = 0; ni < 4; ++ni)
      bfr[ni] = *(const bf16x8*)&Bs[(wc + ni * 16 + fr) * 32 + fk];
#pragma unroll
    for (int mi = 0; mi < 4; ++mi)
#pragma unroll
      for (int ni = 0; ni < 4; ++ni)
        acc[mi][ni] = __builtin_amdgcn_mfma_f32_16x16x32_bf16(
            af[mi], bfr[ni], acc[mi][ni], 0, 0, 0);
    __syncthreads();
  }

  // epilogue: C/D layout col=lane&15, row=(lane>>4)*4+reg  [m89-verified]
  const int fq = (lane >> 4) * 4;
#pragma unroll
  for (int mi = 0; mi < 4; ++mi) {
#pragma unroll
    for (int ni = 0; ni < 4; ++ni) {
      const int row = m0 + wr + mi * 16 + fq;
      const int col = n0 + wc + ni * 16 + fr;
      f32x4 v = acc[mi][ni];
#pragma unroll
      for (int r = 0; r < 4; ++r) {
        float val = v[r];
        size_t idx = (size_t)(row + r) * ldc + col;
        if (EPI == 0) {
          Cb[idx] = f2b(val);
        } else if (EPI == 1) {
          C[idx] = val + res[idx];
        } else if (EPI == 2) {
          Cb[idx] = f2b(fmaxf(val + bias[col], 0.f));
        } else if (EPI == 3) {
          C[idx] = val + bias[col] + res[idx];
        } else { // 4
          C[idx] = C[idx] + val;
        }
      }
    }
  }
}

// ---------------------------------------------------------------------------
// fp32 -> bf16 elementwise convert (vectorized x4)
// ---------------------------------------------------------------------------
__global__ __launch_bounds__(256) void cvt_k(const float* __restrict__ in,
                                             u16* __restrict__ out, int n4) {
  int i = blockIdx.x * 256 + threadIdx.x;
  if (i >= n4) return;
  float4 v = *(const float4*)&in[(size_t)i * 4];
  ushort4 o;
  o.x = f2b(v.x); o.y = f2b(v.y); o.z = f2b(v.z); o.w = f2b(v.w);
  *(ushort4*)&out[(size_t)i * 4] = o;
}

// ---------------------------------------------------------------------------
// transpose-convert: src (R x C) fp32 -> dst (C x R) bf16, batched over z.
// ---------------------------------------------------------------------------
__global__ __launch_bounds__(256) void tconv_k(const float* __restrict__ src,
                                               u16* __restrict__ dst, int R,
                                               int C) {
  __shared__ __align__(16) float t[32][33];
  const size_t bo = (size_t)blockIdx.z * R * C;
  const int r0 = blockIdx.y * 32, c0 = blockIdx.x * 32;
  const int tid = threadIdx.x;
  const int row = tid >> 3, c4 = (tid & 7) * 4;
  float4 v = *(const float4*)&src[bo + (size_t)(r0 + row) * C + c0 + c4];
  t[row][c4 + 0] = v.x; t[row][c4 + 1] = v.y;
  t[row][c4 + 2] = v.z; t[row][c4 + 3] = v.w;
  __syncthreads();
  ushort4 o;
  o.x = f2b(t[c4 + 0][row]); o.y = f2b(t[c4 + 1][row]);
  o.z = f2b(t[c4 + 2][row]); o.w = f2b(t[c4 + 3][row]);
  *(ushort4*)&dst[bo + (size_t)(c0 + row) * R + r0 + c4] = o;
}

// ---------------------------------------------------------------------------
// Attention pass 1 (fp32 compute, bf16 inputs): per (b,h,s) column stats of
// S[q,s] = Q[q]·K[s]/8:  m[s] = max_q S,  l[s] = sum_q exp(S - m[s])
// ---------------------------------------------------------------------------
__global__ __launch_bounds__(256) void attn_stats_k(
    const u16* __restrict__ q, const u16* __restrict__ k,
    float* __restrict__ Mbuf, float* __restrict__ Lbuf) {
  __shared__ __align__(16) float Ks[64][65];
  __shared__ __align__(16) float Qs[64][65];
  const int tid = threadIdx.x, tx = tid & 15, ty = tid >> 4;
  const int s0 = blockIdx.x * 64, h = blockIdx.y, b = blockIdx.z;
  const int bh = b * H_ + h;
  const u16* kbase = k + (size_t)b * T_ * D_ + h * DK_;
  const u16* qbase = q + (size_t)b * T_ * D_ + h * DK_;

#pragma unroll
  for (int l = 0; l < 4; ++l) {
    int idx = tid + l * 256;
    int row = idx >> 4, c4 = (idx & 15) * 4;
    ushort4 v = *(const ushort4*)&kbase[(size_t)(s0 + row) * D_ + c4];
    Ks[row][c4] = b2f(v.x); Ks[row][c4 + 1] = b2f(v.y);
    Ks[row][c4 + 2] = b2f(v.z); Ks[row][c4 + 3] = b2f(v.w);
  }

  float mrun[4], lrun[4];
#pragma unroll
  for (int i = 0; i < 4; ++i) { mrun[i] = -1e30f; lrun[i] = 0.f; }

  for (int q0 = 0; q0 < T_; q0 += 64) {
    __syncthreads();
#pragma unroll
    for (int l = 0; l < 4; ++l) {
      int idx = tid + l * 256;
      int row = idx >> 4, c4 = (idx & 15) * 4;
      ushort4 v = *(const ushort4*)&qbase[(size_t)(q0 + row) * D_ + c4];
      Qs[row][c4] = b2f(v.x); Qs[row][c4 + 1] = b2f(v.y);
      Qs[row][c4 + 2] = b2f(v.z); Qs[row][c4 + 3] = b2f(v.w);
    }
    __syncthreads();

    float acc[4][4] = {};
#pragma unroll 4
    for (int kk = 0; kk < 64; ++kk) {
      float a[4], bq[4];
#pragma unroll
      for (int i = 0; i < 4; ++i) a[i] = Ks[ty * 4 + i][kk];
#pragma unroll
      for (int j = 0; j < 4; ++j) bq[j] = Qs[tx * 4 + j][kk];
#pragma unroll
      for (int i = 0; i < 4; ++i)
#pragma unroll
        for (int j = 0; j < 4; ++j) acc[i][j] += a[i] * bq[j];
    }
#pragma unroll
    for (int i = 0; i < 4; ++i) {
      float tmax = -1e30f;
#pragma unroll
      for (int j = 0; j < 4; ++j) tmax = fmaxf(tmax, acc[i][j] * 0.125f);
      for (int off = 1; off < 16; off <<= 1)
        tmax = fmaxf(tmax, __shfl_xor(tmax, off, 64));
      float nm = fmaxf(mrun[i], tmax);
      float ts = 0.f;
#pragma unroll
      for (int j = 0; j < 4; ++j) ts += expf(acc[i][j] * 0.125f - nm);
      for (int off = 1; off < 16; off <<= 1) ts += __shfl_xor(ts, off, 64);
      lrun[i] = lrun[i] * expf(mrun[i] - nm) + ts;
      mrun[i] = nm;
    }
  }
  if (tx == 0) {
#pragma unroll
    for (int i = 0; i < 4; ++i) {
      Mbuf[(size_t)bh * T_ + s0 + ty * 4 + i] = mrun[i];
      Lbuf[(size_t)bh * T_ + s0 + ty * 4 + i] = lrun[i];
    }
  }
}

// ---------------------------------------------------------------------------
// Attention pass 2: part[q,v] = sum_s exp(S[q,s]-m[s])/l[s] * V[s,v]
// bf16 in, bf16 out (fp32 compute). Output layout (b, t, h*64+v).
// ---------------------------------------------------------------------------
__global__ __launch_bounds__(256) void attn_apply_k(
    const u16* __restrict__ q, const u16* __restrict__ k,
    const u16* __restrict__ v, const float* __restrict__ Mbuf,
    const float* __restrict__ Lbuf, u16* __restrict__ part) {
  __shared__ __align__(16) float Qs[64][65];
  __shared__ __align__(16) float Ks[64][65];
  __shared__ __align__(16) float Vs[64][65];
  __shared__ __align__(16) float Ps[64][65];
  const int tid = threadIdx.x, tx = tid & 15, ty = tid >> 4;
  const int q0 = blockIdx.x * 64, h = blockIdx.y, b = blockIdx.z;
  const int bh = b * H_ + h;
  const u16* qbase = q + (size_t)b * T_ * D_ + h * DK_;
  const u16* kbase = k + (size_t)b * T_ * D_ + h * DK_;
  const u16* vbase = v + (size_t)b * T_ * D_ + h * DK_;

#pragma unroll
  for (int l = 0; l < 4; ++l) {
    int idx = tid + l * 256;
    int row = idx >> 4, c4 = (idx & 15) * 4;
    ushort4 vv = *(const ushort4*)&qbase[(size_t)(q0 + row) * D_ + c4];
    Qs[row][c4] = b2f(vv.x); Qs[row][c4 + 1] = b2f(vv.y);
    Qs[row][c4 + 2] = b2f(vv.z); Qs[row][c4 + 3] = b2f(vv.w);
  }

  float acc2[4][4] = {};
  for (int s0 = 0; s0 < T_; s0 += 64) {
    __syncthreads();
#pragma unroll
    for (int l = 0; l < 4; ++l) {
      int idx = tid + l * 256;
      int row = idx >> 4, c4 = (idx & 15) * 4;
      ushort4 vk = *(const ushort4*)&kbase[(size_t)(s0 + row) * D_ + c4];
      Ks[row][c4] = b2f(vk.x); Ks[row][c4 + 1] = b2f(vk.y);
      Ks[row][c4 + 2] = b2f(vk.z); Ks[row][c4 + 3] = b2f(vk.w);
      ushort4 vv = *(const ushort4*)&vbase[(size_t)(s0 + row) * D_ + c4];
      Vs[row][c4] = b2f(vv.x); Vs[row][c4 + 1] = b2f(vv.y);
      Vs[row][c4 + 2] = b2f(vv.z); Vs[row][c4 + 3] = b2f(vv.w);
    }
    __syncthreads();

    float ms[4], rl[4];
#pragma unroll
    for (int j = 0; j < 4; ++j) {
      ms[j] = Mbuf[(size_t)bh * T_ + s0 + tx * 4 + j];
      rl[j] = 1.f / Lbuf[(size_t)bh * T_ + s0 + tx * 4 + j];
    }

    float t[4][4] = {};
#pragma unroll 4
    for (int kk = 0; kk < 64; ++kk) {
      float a[4], bk[4];
#pragma unroll
      for (int i = 0; i < 4; ++i) a[i] = Qs[ty * 4 + i][kk];
#pragma unroll
      for (int j = 0; j < 4; ++j) bk[j] = Ks[tx * 4 + j][kk];
#pragma unroll
      for (int i = 0; i < 4; ++i)
#pragma unroll
        for (int j = 0; j < 4; ++j) t[i][j] += a[i] * bk[j];
    }
#pragma unroll
    for (int i = 0; i < 4; ++i)
#pragma unroll
      for (int j = 0; j < 4; ++j)
        Ps[ty * 4 + i][tx * 4 + j] = expf(t[i][j] * 0.125f - ms[j]) * rl[j];
    __syncthreads();

#pragma unroll 4
    for (int sl = 0; sl < 64; ++sl) {
      float a[4], bv[4];
#pragma unroll
      for (int i = 0; i < 4; ++i) a[i] = Ps[ty * 4 + i][sl];
#pragma unroll
      for (int j = 0; j < 4; ++j) bv[j] = Vs[sl][tx * 4 + j];
#pragma unroll
      for (int i = 0; i < 4; ++i)
#pragma unroll
        for (int j = 0; j < 4; ++j) acc2[i][j] += a[i] * bv[j];
    }
  }

#pragma unroll
  for (int i = 0; i < 4; ++i) {
    ushort4 w;
    w.x = f2b(acc2[i][0]); w.y = f2b(acc2[i][1]);
    w.z = f2b(acc2[i][2]); w.w = f2b(acc2[i][3]);
    *(ushort4*)&part[(size_t)(b * T_ + q0 + ty * 4 + i) * D_ + h * DK_ + tx * 4] = w;
  }
}

// ---------------------------------------------------------------------------
// Pseudo-norm: y - mean(y) - std(y, ddof=1) per row of 1024. In-place safe.
// WB: also write bf16 copy.
// ---------------------------------------------------------------------------
template <bool WB>
__global__ __launch_bounds__(256) void norm_k(const float* __restrict__ in,
                                              float* __restrict__ out,
                                              u16* __restrict__ ob) {
  __shared__ float red[8];
  const int row = blockIdx.x, tid = threadIdx.x;
  float4 vv = *(const float4*)&in[(size_t)row * D_ + tid * 4];
  float s = vv.x + vv.y + vv.z + vv.w;
  for (int off = 1; off < 64; off <<= 1) s += __shfl_xor(s, off, 64);
  if ((tid & 63) == 0) red[tid >> 6] = s;
  __syncthreads();
  float mean = (red[0] + red[1] + red[2] + red[3]) * (1.f / 1024.f);
  float dx = vv.x - mean, dy = vv.y - mean, dz = vv.z - mean, dw = vv.w - mean;
  float s2 = dx * dx + dy * dy + dz * dz + dw * dw;
  __syncthreads();
  for (int off = 1; off < 64; off <<= 1) s2 += __shfl_xor(s2, off, 64);
  if ((tid & 63) == 0) red[4 + (tid >> 6)] = s2;
  __syncthreads();
  float var = (red[4] + red[5] + red[6] + red[7]) * (1.f / 1023.f);
  float sd = sqrtf(var);
  float4 o = {dx - sd, dy - sd, dz - sd, dw - sd};
  *(float4*)&out[(size_t)row * D_ + tid * 4] = o;
  if (WB) {
    ushort4 q;
    q.x = f2b(o.x); q.y = f2b(o.y); q.z = f2b(o.z); q.w = f2b(o.w);
    *(ushort4*)&ob[(size_t)row * D_ + tid * 4] = q;
  }
}

// ---------------------------------------------------------------------------
extern "C" void kernel_launch(void* const* d_in, const int* in_sizes, int n_in,
                              void* d_out, int out_size, void* d_ws,
                              size_t ws_size, hipStream_t stream) {
  const float* x  = (const float*)d_in[0];
  const float* Wq = (const float*)d_in[1];
  const float* Wk = (const float*)d_in[2];
  const float* Wv = (const float*)d_in[3];
  const float* Wo = (const float*)d_in[4];
  const float* W1 = (const float*)d_in[5];
  const float* b1 = (const float*)d_in[6];
  const float* W2 = (const float*)d_in[7];
  const float* b2 = (const float*)d_in[8];

  char* w = (char*)d_ws;
  u16* qb16   = (u16*)(w + (0ull << 20));
  u16* kb16   = (u16*)(w + (16ull << 20));
  u16* vb16   = (u16*)(w + (32ull << 20));
  u16* xb     = (u16*)(w + (48ull << 20)); // reused as o1b after QKV
  u16* part16 = (u16*)(w + (64ull << 20)); // reused as hc after Wo GEMM
  u16* Wqt    = (u16*)(w + (80ull << 20));
  u16* Wkt    = (u16*)(w + (82ull << 20));
  u16* Wvt    = (u16*)(w + (84ull << 20));
  u16* Wot    = (u16*)(w + (86ull << 20));
  u16* W1b    = (u16*)(w + (88ull << 20));
  u16* W2b    = (u16*)(w + (96ull << 20));
  float* Mb   = (float*)(w + (104ull << 20));
  float* Lb   = Mb + (size_t)B_ * H_ * T_;
  u16* o1b = xb;
  u16* hc  = part16;
  float* o1 = (float*)d_out;

  dim3 thr(256);

  // ---- convert weights/activations to bf16 (Bt layout = N x K) ----
  int n4x = (M_ * D_) / 4;
  cvt_k<<<dim3((n4x + 255) / 256), thr, 0, stream>>>(x, xb, n4x);
  tconv_k<<<dim3(2, 32, 16), thr, 0, stream>>>(Wq, Wqt, 1024, 64);
  tconv_k<<<dim3(2, 32, 16), thr, 0, stream>>>(Wk, Wkt, 1024, 64);
  tconv_k<<<dim3(2, 32, 16), thr, 0, stream>>>(Wv, Wvt, 1024, 64);
  tconv_k<<<dim3(32, 32, 1), thr, 0, stream>>>(Wo, Wot, 1024, 1024);
  int n4w = (FF_ * D_) / 4;
  cvt_k<<<dim3((n4w + 255) / 256), thr, 0, stream>>>(W1, W1b, n4w);
  cvt_k<<<dim3((n4w + 255) / 256), thr, 0, stream>>>(W2, W2b, n4w);

  // ---- QKV projections (bf16 MFMA) ----
  dim3 g128(D_ / 128, M_ / 128); // (8, 64)
  gemm16_k<0><<<g128, thr, 0, stream>>>(xb, Wqt, M_, D_, D_, D_, D_,
                                        nullptr, D_, qb16, nullptr, nullptr);
  gemm16_k<0><<<g128, thr, 0, stream>>>(xb, Wkt, M_, D_, D_, D_, D_,
                                        nullptr, D_, kb16, nullptr, nullptr);
  gemm16_k<0><<<g128, thr, 0, stream>>>(xb, Wvt, M_, D_, D_, D_, D_,
                                        nullptr, D_, vb16, nullptr, nullptr);

  // ---- attention (query-axis softmax, two-pass) ----
  dim3 ga(T_ / 64, H_, B_);
  attn_stats_k<<<ga, thr, 0, stream>>>(qb16, kb16, Mb, Lb);
  attn_apply_k<<<ga, thr, 0, stream>>>(qb16, kb16, vb16, Mb, Lb, part16);

  // ---- out1 = part @ Wo + x -> d_out (fp32); pseudo-norm + bf16 copy ----
  gemm16_k<1><<<g128, thr, 0, stream>>>(part16, Wot, M_, D_, D_, D_, D_,
                                        o1, D_, nullptr, x, nullptr);
  norm_k<true><<<dim3(M_), thr, 0, stream>>>(o1, o1, o1b);

  // ---- FF in 4 inner-dim chunks of 1024 ----
  for (int c = 0; c < 4; ++c) {
    const u16* W1c = W1b + (size_t)c * 1024 * 1024; // rows c*1024.. (N x K)
    const u16* W2c = W2b + (size_t)c * 1024;        // k-window offset (ldb=4096)
    gemm16_k<2><<<g128, thr, 0, stream>>>(o1b, W1c, M_, 1024, 1024, 1024, 1024,
                                          nullptr, 1024, hc, nullptr,
                                          b1 + c * 1024);
    if (c == 0) {
      gemm16_k<3><<<g128, thr, 0, stream>>>(hc, W2c, M_, 1024, 1024, 1024, FF_,
                                            o1, D_, nullptr, o1, b2);
    } else {
      gemm16_k<4><<<g128, thr, 0, stream>>>(hc, W2c, M_, 1024, 1024, 1024, FF_,
                                            o1, D_, nullptr, nullptr, nullptr);
    }
  }

  // ---- final pseudo-norm in place on d_out ----
  norm_k<false><<<dim3(M_), thr, 0, stream>>>(o1, o1, nullptr);
}

// Round 4
// 757.773 us; speedup vs baseline: 5.2118x; 2.1785x over previous
//
#include <hip/hip_runtime.h>
#include <math.h>

// Encoder block. B=8, T=1024, D=1024, H=16, dk=dv=64, FF=4096.
// softmax in reference is over the QUERY axis (axis=2 of (B,H,Tq,Ts)).
// Round 4: attention moved to bf16 MFMA. No-max softmax (logits bounded),
// two-pass: (1) l[s] = sum_q exp(S/8) via S^T = mfma(K,Q); (2) P = exp*rl,
// P @ V via LDS-roundtripped P and per-head-transposed V (from V-GEMM epi).
//
// Workspace (~105 MB):
//  [0,16M)  qb16   [16,32M) kb16   [32,48M) Vt (b,h,v,s bf16)
//  [48,64M) xb16 -> o1b16   [64,80M) part16 -> hc
//  [80,86M) Wqt/Wkt/Wvt  [86,88M) Wot  [88,96M) W1b  [96,104M) W2b
//  [104M..) Lrcp (1/l, fp32, B*H*T)

#define B_ 8
#define T_ 1024
#define D_ 1024
#define H_ 16
#define DK_ 64
#define FF_ 4096
#define M_ (B_ * T_) // 8192

typedef unsigned short u16;
typedef __attribute__((ext_vector_type(8))) short bf16x8;
typedef __attribute__((ext_vector_type(4))) float f32x4;

__device__ __forceinline__ float b2f(u16 u) {
  union { unsigned int i; float f; } x;
  x.i = ((unsigned int)u) << 16;
  return x.f;
}
__device__ __forceinline__ u16 f2b(float f) {
  union { float f; unsigned int i; } x;
  x.f = f;
  unsigned int r = (x.i + 0x7FFFu + ((x.i >> 16) & 1u)) >> 16; // RNE
  return (u16)r;
}

typedef __attribute__((address_space(1))) const void gas_void;
typedef __attribute__((address_space(3))) void las_void;
__device__ __forceinline__ void gload16(const void* g, void* l) {
  __builtin_amdgcn_global_load_lds((gas_void*)g, (las_void*)l, 16, 0, 0);
}

// ---------------------------------------------------------------------------
// bf16 MFMA GEMM, m97 structure. C[M,N] = A[M,K] @ Bt[N,K]^T
// EPI: 0: Cb=bf16(acc)            1: C=acc+res
//      2: Cb=bf16(relu(acc+bias)) 3: C=acc+bias+res   4: C+=acc
//      5: Cb = per-head transposed bf16 (for V): Cb[((b*16+h)*64+v)*T + t]
// ---------------------------------------------------------------------------
template <int EPI>
__global__ __launch_bounds__(256) void gemm16_k(
    const u16* __restrict__ A, const u16* __restrict__ Bt,
    int M, int N, int K, int lda, int ldb,
    float* __restrict__ C, int ldc, u16* __restrict__ Cb,
    const float* __restrict__ res, const float* __restrict__ bias) {
  __shared__ __align__(16) u16 As[128 * 32];
  __shared__ __align__(16) u16 Bs[128 * 32];

  const int tid = threadIdx.x;
  const int lane = tid & 63, wv = tid >> 6;
  const int m0 = blockIdx.y * 128, n0 = blockIdx.x * 128;
  const int wr = (wv >> 1) * 64, wc = (wv & 1) * 64;

  f32x4 acc[4][4];
#pragma unroll
  for (int i = 0; i < 4; ++i)
#pragma unroll
    for (int j = 0; j < 4; ++j) acc[i][j] = (f32x4){0.f, 0.f, 0.f, 0.f};

  const int srow = wv * 16 + (lane >> 2);
  const int scol = (lane & 3) * 8;
  const int fr = lane & 15, fk = (lane >> 4) * 8;

  for (int k0 = 0; k0 < K; k0 += 32) {
    gload16(&A[(size_t)(m0 + srow) * lda + k0 + scol], &As[wv * 512]);
    gload16(&A[(size_t)(m0 + srow + 64) * lda + k0 + scol], &As[2048 + wv * 512]);
    gload16(&Bt[(size_t)(n0 + srow) * ldb + k0 + scol], &Bs[wv * 512]);
    gload16(&Bt[(size_t)(n0 + srow + 64) * ldb + k0 + scol], &Bs[2048 + wv * 512]);
    __syncthreads();

    bf16x8 af[4], bfr[4];
#pragma unroll
    for (int mi = 0; mi < 4; ++mi)
      af[mi] = *(const bf16x8*)&As[(wr + mi * 16 + fr) * 32 + fk];
#pragma unroll
    for (int ni = 0; ni < 4; ++ni)
      bfr[ni] = *(const bf16x8*)&Bs[(wc + ni * 16 + fr) * 32 + fk];
#pragma unroll
    for (int mi = 0; mi < 4; ++mi)
#pragma unroll
      for (int ni = 0; ni < 4; ++ni)
        acc[mi][ni] = __builtin_amdgcn_mfma_f32_16x16x32_bf16(
            af[mi], bfr[ni], acc[mi][ni], 0, 0, 0);
    __syncthreads();
  }

  const int fq = (lane >> 4) * 4;
#pragma unroll
  for (int mi = 0; mi < 4; ++mi) {
#pragma unroll
    for (int ni = 0; ni < 4; ++ni) {
      const int row = m0 + wr + mi * 16 + fq;
      const int col = n0 + wc + ni * 16 + fr;
      f32x4 v = acc[mi][ni];
      if (EPI == 5) {
        ushort4 w;
        w.x = f2b(v[0]); w.y = f2b(v[1]); w.z = f2b(v[2]); w.w = f2b(v[3]);
        size_t vidx = (((size_t)(row >> 10) * 16 + (col >> 6)) * 64 +
                       (col & 63)) * (size_t)T_ + (row & 1023);
        *(ushort4*)&Cb[vidx] = w;
      } else {
#pragma unroll
        for (int r = 0; r < 4; ++r) {
          float val = v[r];
          size_t idx = (size_t)(row + r) * ldc + col;
          if (EPI == 0) {
            Cb[idx] = f2b(val);
          } else if (EPI == 1) {
            C[idx] = val + res[idx];
          } else if (EPI == 2) {
            Cb[idx] = f2b(fmaxf(val + bias[col], 0.f));
          } else if (EPI == 3) {
            C[idx] = val + bias[col] + res[idx];
          } else if (EPI == 4) {
            C[idx] = C[idx] + val;
          }
        }
      }
    }
  }
}

// ---------------------------------------------------------------------------
// fp32 -> bf16 elementwise convert
// ---------------------------------------------------------------------------
__global__ __launch_bounds__(256) void cvt_k(const float* __restrict__ in,
                                             u16* __restrict__ out, int n4) {
  int i = blockIdx.x * 256 + threadIdx.x;
  if (i >= n4) return;
  float4 v = *(const float4*)&in[(size_t)i * 4];
  ushort4 o;
  o.x = f2b(v.x); o.y = f2b(v.y); o.z = f2b(v.z); o.w = f2b(v.w);
  *(ushort4*)&out[(size_t)i * 4] = o;
}

// ---------------------------------------------------------------------------
// transpose-convert: src (R x C) fp32 -> dst (C x R) bf16, batched over z.
// ---------------------------------------------------------------------------
__global__ __launch_bounds__(256) void tconv_k(const float* __restrict__ src,
                                               u16* __restrict__ dst, int R,
                                               int C) {
  __shared__ __align__(16) float t[32][33];
  const size_t bo = (size_t)blockIdx.z * R * C;
  const int r0 = blockIdx.y * 32, c0 = blockIdx.x * 32;
  const int tid = threadIdx.x;
  const int row = tid >> 3, c4 = (tid & 7) * 4;
  float4 v = *(const float4*)&src[bo + (size_t)(r0 + row) * C + c0 + c4];
  t[row][c4 + 0] = v.x; t[row][c4 + 1] = v.y;
  t[row][c4 + 2] = v.z; t[row][c4 + 3] = v.w;
  __syncthreads();
  ushort4 o;
  o.x = f2b(t[c4 + 0][row]); o.y = f2b(t[c4 + 1][row]);
  o.z = f2b(t[c4 + 2][row]); o.w = f2b(t[c4 + 3][row]);
  *(ushort4*)&dst[bo + (size_t)(c0 + row) * R + r0 + c4] = o;
}

// ---------------------------------------------------------------------------
// Attention pass 1 (MFMA): Lrcp[b,h,s] = 1 / sum_q exp(S[q,s]/8)
// S^T tile = mfma(A=K rows(s), B=Q rows(q)). K-frags in registers; Q staged
// to LDS via gload16 with pre-swizzled source (slot ^= row&7).
// Grid (T/128, H, B), 256 thr = 4 waves (quadrants: wr on s, wc on q).
// ---------------------------------------------------------------------------
__global__ __launch_bounds__(256) void attn_lsum_k(
    const u16* __restrict__ q, const u16* __restrict__ k,
    float* __restrict__ Lrcp) {
  __shared__ __align__(16) u16 Qs[128 * 64]; // 16 KB, swizzled
  __shared__ float Lsh[2][128];
  const int tid = threadIdx.x, lane = tid & 63, wv = tid >> 6;
  const int s0 = blockIdx.x * 128, h = blockIdx.y, b = blockIdx.z;
  const int bh = b * H_ + h;
  const u16* qbase = q + (size_t)b * T_ * D_ + h * DK_;
  const u16* kbase = k + (size_t)b * T_ * D_ + h * DK_;

  const int wr = (wv >> 1) * 64, wc = (wv & 1) * 64;
  const int fr = lane & 15, fs8 = (lane >> 4) * 8, fq = (lane >> 4) * 4;

  // K fragments in registers (fixed for the block)
  bf16x8 kf[4][2];
#pragma unroll
  for (int mi = 0; mi < 4; ++mi)
#pragma unroll
    for (int ks = 0; ks < 2; ++ks)
      kf[mi][ks] = *(const bf16x8*)&kbase[(size_t)(s0 + wr + mi * 16 + fr) * D_ +
                                          ks * 32 + fs8];

  float lrun[4][4];
#pragma unroll
  for (int mi = 0; mi < 4; ++mi)
#pragma unroll
    for (int r = 0; r < 4; ++r) lrun[mi][r] = 0.f;

  const int srow = wv * 8 + (lane >> 3);                  // + it*32
  const int sscol = ((lane & 7) ^ ((lane >> 3) & 7)) * 8; // pre-swizzled src

  for (int q0 = 0; q0 < T_; q0 += 128) {
    __syncthreads(); // prev-iter Qs reads done
#pragma unroll
    for (int it = 0; it < 4; ++it)
      gload16(&qbase[(size_t)(q0 + it * 32 + srow) * D_ + sscol],
              &Qs[(it * 32 + wv * 8) * 64]);
    __syncthreads();

    f32x4 acc[4][4];
#pragma unroll
    for (int mi = 0; mi < 4; ++mi)
#pragma unroll
      for (int ni = 0; ni < 4; ++ni) acc[mi][ni] = (f32x4){0.f, 0.f, 0.f, 0.f};

#pragma unroll
    for (int ks = 0; ks < 2; ++ks) {
      bf16x8 qf[4];
#pragma unroll
      for (int ni = 0; ni < 4; ++ni) {
        int qr = wc + ni * 16 + fr;
        int slot = (ks * 4 + (lane >> 4)) ^ (qr & 7);
        qf[ni] = *(const bf16x8*)&Qs[qr * 64 + slot * 8];
      }
#pragma unroll
      for (int mi = 0; mi < 4; ++mi)
#pragma unroll
        for (int ni = 0; ni < 4; ++ni)
          acc[mi][ni] = __builtin_amdgcn_mfma_f32_16x16x32_bf16(
              kf[mi][ks], qf[ni], acc[mi][ni], 0, 0, 0);
    }
#pragma unroll
    for (int mi = 0; mi < 4; ++mi)
#pragma unroll
      for (int r = 0; r < 4; ++r) {
        float e = 0.f;
#pragma unroll
        for (int ni = 0; ni < 4; ++ni) e += __expf(acc[mi][ni][r] * 0.125f);
        lrun[mi][r] += e;
      }
  }

  // reduce over the 16 q-column lanes; combine wave halves via LDS
#pragma unroll
  for (int mi = 0; mi < 4; ++mi)
#pragma unroll
    for (int r = 0; r < 4; ++r) {
      float s = lrun[mi][r];
      s += __shfl_xor(s, 1, 64); s += __shfl_xor(s, 2, 64);
      s += __shfl_xor(s, 4, 64); s += __shfl_xor(s, 8, 64);
      if (fr == 0) Lsh[wv & 1][wr + mi * 16 + fq + r] = s;
    }
  __syncthreads();
  if (tid < 128)
    Lrcp[(size_t)bh * T_ + s0 + tid] = 1.f / (Lsh[0][tid] + Lsh[1][tid]);
}

// ---------------------------------------------------------------------------
// Attention pass 2 (MFMA): part[q,v] = sum_s exp(S[q,s]/8)*Lrcp[s] * V[s,v]
// Per q-tile of 128: iterate s-tiles of 128: S = mfma(Q,K); P = exp*rl ->
// LDS (swizzled); part += mfma(P, Vt). Q-frags in registers. 64 KB LDS.
// ---------------------------------------------------------------------------
__global__ __launch_bounds__(256) void attn_pv_k(
    const u16* __restrict__ q, const u16* __restrict__ k,
    const u16* __restrict__ vt, const float* __restrict__ Lrcp,
    u16* __restrict__ part) {
  __shared__ __align__(16) u16 Ks[128 * 64];  // 16 KB swizzled
  __shared__ __align__(16) u16 Vs[64 * 128];  // 16 KB swizzled (v-major)
  __shared__ __align__(16) u16 Ps[128 * 128]; // 32 KB swizzled
  const int tid = threadIdx.x, lane = tid & 63, wv = tid >> 6;
  const int q0 = blockIdx.x * 128, h = blockIdx.y, b = blockIdx.z;
  const int bh = b * H_ + h;
  const u16* qbase = q + (size_t)b * T_ * D_ + h * DK_;
  const u16* kbase = k + (size_t)b * T_ * D_ + h * DK_;
  const u16* vtb = vt + (size_t)bh * DK_ * T_;
  const float* lb = Lrcp + (size_t)bh * T_;

  const int wr = (wv >> 1) * 64, wc = (wv & 1) * 64; // S quadrant: q, s
  const int fr = lane & 15, fs8 = (lane >> 4) * 8, fq = (lane >> 4) * 4;

  // Q fragments in registers (fixed for the block)
  bf16x8 qf[4][2];
#pragma unroll
  for (int mi = 0; mi < 4; ++mi)
#pragma unroll
    for (int ks = 0; ks < 2; ++ks)
      qf[mi][ks] = *(const bf16x8*)&qbase[(size_t)(q0 + wr + mi * 16 + fr) * D_ +
                                          ks * 32 + fs8];

  f32x4 acc2[2][4]; // PV out: rows q0 + wv*32 + mi2*16, cols ni2*16
#pragma unroll
  for (int i = 0; i < 2; ++i)
#pragma unroll
    for (int j = 0; j < 4; ++j) acc2[i][j] = (f32x4){0.f, 0.f, 0.f, 0.f};

  const int ksrow = wv * 8 + (lane >> 3);                  // + it*32
  const int kscol = ((lane & 7) ^ ((lane >> 3) & 7)) * 8;  // pre-swizzled

  for (int s0 = 0; s0 < T_; s0 += 128) {
    __syncthreads(); // prev-iter Ks/Vs/Ps reads done
#pragma unroll
    for (int it = 0; it < 4; ++it)
      gload16(&kbase[(size_t)(s0 + it * 32 + ksrow) * D_ + kscol],
              &Ks[(it * 32 + wv * 8) * 64]);
#pragma unroll
    for (int it = 0; it < 4; ++it) {
      int v = it * 16 + wv * 4 + (lane >> 4);
      int sslot = (lane & 15) ^ (v & 7);
      gload16(&vtb[(size_t)v * T_ + s0 + sslot * 8],
              &Vs[(it * 16 + wv * 4) * 128]);
    }
    __syncthreads();

    // S quadrant
    f32x4 accs[4][4];
#pragma unroll
    for (int mi = 0; mi < 4; ++mi)
#pragma unroll
      for (int ni = 0; ni < 4; ++ni) accs[mi][ni] = (f32x4){0.f, 0.f, 0.f, 0.f};
#pragma unroll
    for (int ks = 0; ks < 2; ++ks) {
      bf16x8 kfr[4];
#pragma unroll
      for (int ni = 0; ni < 4; ++ni) {
        int sr = wc + ni * 16 + fr;
        int slot = (ks * 4 + (lane >> 4)) ^ (sr & 7);
        kfr[ni] = *(const bf16x8*)&Ks[sr * 64 + slot * 8];
      }
#pragma unroll
      for (int mi = 0; mi < 4; ++mi)
#pragma unroll
        for (int ni = 0; ni < 4; ++ni)
          accs[mi][ni] = __builtin_amdgcn_mfma_f32_16x16x32_bf16(
              qf[mi][ks], kfr[ni], accs[mi][ni], 0, 0, 0);
    }

    // P = exp(S/8) * rl[s] -> Ps (swizzled scalar writes)
#pragma unroll
    for (int ni = 0; ni < 4; ++ni) {
      float rl = lb[s0 + wc + ni * 16 + fr];
      int scol = wc + ni * 16 + fr;
#pragma unroll
      for (int mi = 0; mi < 4; ++mi) {
#pragma unroll
        for (int r = 0; r < 4; ++r) {
          int qrow = wr + mi * 16 + fq + r;
          u16 pv = f2b(__expf(accs[mi][ni][r] * 0.125f) * rl);
          int eoff = qrow * 128 + ((((scol << 1) ^ ((qrow & 7) << 4))) >> 1);
          Ps[eoff] = pv;
        }
      }
    }
    __syncthreads();

    // acc2 += P(rows wv*32..+32) @ V
#pragma unroll
    for (int ks2 = 0; ks2 < 4; ++ks2) {
      bf16x8 pa[2], vb2[4];
#pragma unroll
      for (int mi2 = 0; mi2 < 2; ++mi2) {
        int qr = wv * 32 + mi2 * 16 + fr;
        int slot = (ks2 * 4 + (lane >> 4)) ^ (qr & 7);
        pa[mi2] = *(const bf16x8*)&Ps[qr * 128 + slot * 8];
      }
#pragma unroll
      for (int ni2 = 0; ni2 < 4; ++ni2) {
        int v = ni2 * 16 + fr;
        int slot = (ks2 * 4 + (lane >> 4)) ^ (v & 7);
        vb2[ni2] = *(const bf16x8*)&Vs[v * 128 + slot * 8];
      }
#pragma unroll
      for (int mi2 = 0; mi2 < 2; ++mi2)
#pragma unroll
        for (int ni2 = 0; ni2 < 4; ++ni2)
          acc2[mi2][ni2] = __builtin_amdgcn_mfma_f32_16x16x32_bf16(
              pa[mi2], vb2[ni2], acc2[mi2][ni2], 0, 0, 0);
    }
  }

  // epilogue: part[(b*T + q)][h*64 + v] bf16
#pragma unroll
  for (int mi2 = 0; mi2 < 2; ++mi2)
#pragma unroll
    for (int ni2 = 0; ni2 < 4; ++ni2)
#pragma unroll
      for (int r = 0; r < 4; ++r) {
        int qrow = q0 + wv * 32 + mi2 * 16 + fq + r;
        int v = ni2 * 16 + fr;
        part[(size_t)(b * T_ + qrow) * D_ + h * DK_ + v] =
            f2b(acc2[mi2][ni2][r]);
      }
}

// ---------------------------------------------------------------------------
// Pseudo-norm: y - mean(y) - std(y, ddof=1) per row of 1024. In-place safe.
// ---------------------------------------------------------------------------
template <bool WB>
__global__ __launch_bounds__(256) void norm_k(const float* __restrict__ in,
                                              float* __restrict__ out,
                                              u16* __restrict__ ob) {
  __shared__ float red[8];
  const int row = blockIdx.x, tid = threadIdx.x;
  float4 vv = *(const float4*)&in[(size_t)row * D_ + tid * 4];
  float s = vv.x + vv.y + vv.z + vv.w;
  for (int off = 1; off < 64; off <<= 1) s += __shfl_xor(s, off, 64);
  if ((tid & 63) == 0) red[tid >> 6] = s;
  __syncthreads();
  float mean = (red[0] + red[1] + red[2] + red[3]) * (1.f / 1024.f);
  float dx = vv.x - mean, dy = vv.y - mean, dz = vv.z - mean, dw = vv.w - mean;
  float s2 = dx * dx + dy * dy + dz * dz + dw * dw;
  __syncthreads();
  for (int off = 1; off < 64; off <<= 1) s2 += __shfl_xor(s2, off, 64);
  if ((tid & 63) == 0) red[4 + (tid >> 6)] = s2;
  __syncthreads();
  float var = (red[4] + red[5] + red[6] + red[7]) * (1.f / 1023.f);
  float sd = sqrtf(var);
  float4 o = {dx - sd, dy - sd, dz - sd, dw - sd};
  *(float4*)&out[(size_t)row * D_ + tid * 4] = o;
  if (WB) {
    ushort4 q;
    q.x = f2b(o.x); q.y = f2b(o.y); q.z = f2b(o.z); q.w = f2b(o.w);
    *(ushort4*)&ob[(size_t)row * D_ + tid * 4] = q;
  }
}

// ---------------------------------------------------------------------------
extern "C" void kernel_launch(void* const* d_in, const int* in_sizes, int n_in,
                              void* d_out, int out_size, void* d_ws,
                              size_t ws_size, hipStream_t stream) {
  const float* x  = (const float*)d_in[0];
  const float* Wq = (const float*)d_in[1];
  const float* Wk = (const float*)d_in[2];
  const float* Wv = (const float*)d_in[3];
  const float* Wo = (const float*)d_in[4];
  const float* W1 = (const float*)d_in[5];
  const float* b1 = (const float*)d_in[6];
  const float* W2 = (const float*)d_in[7];
  const float* b2 = (const float*)d_in[8];

  char* w = (char*)d_ws;
  u16* qb16   = (u16*)(w + (0ull << 20));
  u16* kb16   = (u16*)(w + (16ull << 20));
  u16* Vt     = (u16*)(w + (32ull << 20)); // (b,h,v,s) bf16
  u16* xb     = (u16*)(w + (48ull << 20)); // reused as o1b after QKV
  u16* part16 = (u16*)(w + (64ull << 20)); // reused as hc after Wo GEMM
  u16* Wqt    = (u16*)(w + (80ull << 20));
  u16* Wkt    = (u16*)(w + (82ull << 20));
  u16* Wvt    = (u16*)(w + (84ull << 20));
  u16* Wot    = (u16*)(w + (86ull << 20));
  u16* W1b    = (u16*)(w + (88ull << 20));
  u16* W2b    = (u16*)(w + (96ull << 20));
  float* Lrcp = (float*)(w + (104ull << 20));
  u16* o1b = xb;
  u16* hc  = part16;
  float* o1 = (float*)d_out;

  dim3 thr(256);

  // ---- convert weights/activations to bf16 (Bt layout = N x K) ----
  int n4x = (M_ * D_) / 4;
  cvt_k<<<dim3((n4x + 255) / 256), thr, 0, stream>>>(x, xb, n4x);
  tconv_k<<<dim3(2, 32, 16), thr, 0, stream>>>(Wq, Wqt, 1024, 64);
  tconv_k<<<dim3(2, 32, 16), thr, 0, stream>>>(Wk, Wkt, 1024, 64);
  tconv_k<<<dim3(2, 32, 16), thr, 0, stream>>>(Wv, Wvt, 1024, 64);
  tconv_k<<<dim3(32, 32, 1), thr, 0, stream>>>(Wo, Wot, 1024, 1024);
  int n4w = (FF_ * D_) / 4;
  cvt_k<<<dim3((n4w + 255) / 256), thr, 0, stream>>>(W1, W1b, n4w);
  cvt_k<<<dim3((n4w + 255) / 256), thr, 0, stream>>>(W2, W2b, n4w);

  // ---- QKV projections (V writes per-head transposed Vt) ----
  dim3 g128(D_ / 128, M_ / 128);
  gemm16_k<0><<<g128, thr, 0, stream>>>(xb, Wqt, M_, D_, D_, D_, D_,
                                        nullptr, D_, qb16, nullptr, nullptr);
  gemm16_k<0><<<g128, thr, 0, stream>>>(xb, Wkt, M_, D_, D_, D_, D_,
                                        nullptr, D_, kb16, nullptr, nullptr);
  gemm16_k<5><<<g128, thr, 0, stream>>>(xb, Wvt, M_, D_, D_, D_, D_,
                                        nullptr, D_, Vt, nullptr, nullptr);

  // ---- attention (query-axis softmax, no-max two-pass, MFMA) ----
  dim3 ga(T_ / 128, H_, B_);
  attn_lsum_k<<<ga, thr, 0, stream>>>(qb16, kb16, Lrcp);
  attn_pv_k<<<ga, thr, 0, stream>>>(qb16, kb16, Vt, Lrcp, part16);

  // ---- out1 = part @ Wo + x -> d_out (fp32); pseudo-norm + bf16 copy ----
  gemm16_k<1><<<g128, thr, 0, stream>>>(part16, Wot, M_, D_, D_, D_, D_,
                                        o1, D_, nullptr, x, nullptr);
  norm_k<true><<<dim3(M_), thr, 0, stream>>>(o1, o1, o1b);

  // ---- FF in 4 inner-dim chunks of 1024 ----
  for (int c = 0; c < 4; ++c) {
    const u16* W1c = W1b + (size_t)c * 1024 * 1024;
    const u16* W2c = W2b + (size_t)c * 1024;
    gemm16_k<2><<<g128, thr, 0, stream>>>(o1b, W1c, M_, 1024, 1024, 1024, 1024,
                                          nullptr, 1024, hc, nullptr,
                                          b1 + c * 1024);
    if (c == 0) {
      gemm16_k<3><<<g128, thr, 0, stream>>>(hc, W2c, M_, 1024, 1024, 1024, FF_,
                                            o1, D_, nullptr, o1, b2);
    } else {
      gemm16_k<4><<<g128, thr, 0, stream>>>(hc, W2c, M_, 1024, 1024, 1024, FF_,
                                            o1, D_, nullptr, nullptr, nullptr);
    }
  }

  // ---- final pseudo-norm in place on d_out ----
  norm_k<false><<<dim3(M_), thr, 0, stream>>>(o1, o1, nullptr);
}

// Round 5
// 649.188 us; speedup vs baseline: 6.0836x; 1.1673x over previous
//
#include <hip/hip_runtime.h>
#include <math.h>

// Encoder block. B=8, T=1024, D=1024, H=16, dk=dv=64, FF=4096.
// softmax in reference is over the QUERY axis (axis=2 of (B,H,Tq,Ts)).
// Round 5: 2-phase double-buffered GEMM (prefetch next K-tile before compute,
// 1 barrier/K-step); fused QKV (N=3072, epilogue split); FF in 2 chunks of
// 2048; attention exp-chain folded to fma+exp2 via lg2(1/l) stats.
//
// Workspace (~105 MB):
//  [0,16M)  qb16 -> o1b16 after attention
//  [16,32M) kb16 --\ hc (32 MB, FF hidden chunk) after attention
//  [32,48M) Vt ----/
//  [48,64M) xb16 (dead after QKV)
//  [64,80M) part16 (dead after Wo GEMM)
//  [80,86M) Wqt/Wkt/Wvt (contiguous 3072 x 1024 Bt)  [86,88M) Wot
//  [88,96M) W1b  [96,104M) W2b   [104M..) Lg (=-log2 l, fp32, B*H*T)

#define B_ 8
#define T_ 1024
#define D_ 1024
#define H_ 16
#define DK_ 64
#define FF_ 4096
#define M_ (B_ * T_) // 8192

typedef unsigned short u16;
typedef __attribute__((ext_vector_type(8))) short bf16x8;
typedef __attribute__((ext_vector_type(4))) float f32x4;

#define QSZ 8388608ull // 8192*1024 elements (16 MB bf16)

__device__ __forceinline__ float b2f(u16 u) {
  union { unsigned int i; float f; } x;
  x.i = ((unsigned int)u) << 16;
  return x.f;
}
__device__ __forceinline__ u16 f2b(float f) {
  union { float f; unsigned int i; } x;
  x.f = f;
  unsigned int r = (x.i + 0x7FFFu + ((x.i >> 16) & 1u)) >> 16; // RNE
  return (u16)r;
}
__device__ __forceinline__ float fexp2(float x) {
#if __has_builtin(__builtin_amdgcn_exp2f)
  return __builtin_amdgcn_exp2f(x);
#else
  return exp2f(x);
#endif
}
#define C_QK 0.1803368801111244f // 0.125 * log2(e)

typedef __attribute__((address_space(1))) const void gas_void;
typedef __attribute__((address_space(3))) void las_void;
__device__ __forceinline__ void gload16(const void* g, void* l) {
  __builtin_amdgcn_global_load_lds((gas_void*)g, (las_void*)l, 16, 0, 0);
}

// ---------------------------------------------------------------------------
// bf16 MFMA GEMM, 2-phase double-buffered. C[M,N] = A[M,K] @ Bt[N,K]^T
// 128x128 tile, BK=32, 256 thr = 4 waves (64x64 quadrants, 4x4 16x16 frags).
// Per K-step: prefetch next tile (gload_lds) -> ds_read+MFMA current ->
// one barrier (compiler drains vmcnt+lgkm there).
// EPI: 1: C=acc+res   2: Cb=bf16(relu(acc+bias))   3: C=acc+bias+res
//      4: C+=acc      6: fused-QKV split (Cb base = qb16; +QSZ k; +2QSZ Vt)
// ---------------------------------------------------------------------------
template <int EPI>
__global__ __launch_bounds__(256) void gemm16_k(
    const u16* __restrict__ A, const u16* __restrict__ Bt,
    int M, int N, int K, int lda, int ldb,
    float* __restrict__ C, int ldc, u16* __restrict__ Cb,
    const float* __restrict__ res, const float* __restrict__ bias) {
  __shared__ __align__(16) u16 As[2][128 * 32]; // 2 x 8 KB
  __shared__ __align__(16) u16 Bs[2][128 * 32];

  const int tid = threadIdx.x;
  const int lane = tid & 63, wv = tid >> 6;
  const int m0 = blockIdx.y * 128, n0 = blockIdx.x * 128;
  const int wr = (wv >> 1) * 64, wc = (wv & 1) * 64;

  f32x4 acc[4][4];
#pragma unroll
  for (int i = 0; i < 4; ++i)
#pragma unroll
    for (int j = 0; j < 4; ++j) acc[i][j] = (f32x4){0.f, 0.f, 0.f, 0.f};

  const int srow = wv * 16 + (lane >> 2);
  const int scol = (lane & 3) * 8;
  const int fr = lane & 15, fk = (lane >> 4) * 8;

  const u16* gA0 = &A[(size_t)(m0 + srow) * lda + scol];
  const u16* gA1 = &A[(size_t)(m0 + srow + 64) * lda + scol];
  const u16* gB0 = &Bt[(size_t)(n0 + srow) * ldb + scol];
  const u16* gB1 = &Bt[(size_t)(n0 + srow + 64) * ldb + scol];

  // prologue: stage tile 0 into buf 0
  gload16(gA0, &As[0][wv * 512]);
  gload16(gA1, &As[0][2048 + wv * 512]);
  gload16(gB0, &Bs[0][wv * 512]);
  gload16(gB1, &Bs[0][2048 + wv * 512]);
  __syncthreads();

  int cur = 0;
  for (int k0 = 0; k0 < K; k0 += 32) {
    if (k0 + 32 < K) { // prefetch next K-tile into other buffer
      int nx = cur ^ 1, ko = k0 + 32;
      gload16(gA0 + ko, &As[nx][wv * 512]);
      gload16(gA1 + ko, &As[nx][2048 + wv * 512]);
      gload16(gB0 + ko, &Bs[nx][wv * 512]);
      gload16(gB1 + ko, &Bs[nx][2048 + wv * 512]);
    }
    bf16x8 af[4], bfr[4];
#pragma unroll
    for (int mi = 0; mi < 4; ++mi)
      af[mi] = *(const bf16x8*)&As[cur][(wr + mi * 16 + fr) * 32 + fk];
#pragma unroll
    for (int ni = 0; ni < 4; ++ni)
      bfr[ni] = *(const bf16x8*)&Bs[cur][(wc + ni * 16 + fr) * 32 + fk];
#pragma unroll
    for (int mi = 0; mi < 4; ++mi)
#pragma unroll
      for (int ni = 0; ni < 4; ++ni)
        acc[mi][ni] = __builtin_amdgcn_mfma_f32_16x16x32_bf16(
            af[mi], bfr[ni], acc[mi][ni], 0, 0, 0);
    __syncthreads(); // drains prefetch (vmcnt0) + protects LDS reuse
    cur ^= 1;
  }

  const int fq = (lane >> 4) * 4;
#pragma unroll
  for (int mi = 0; mi < 4; ++mi) {
#pragma unroll
    for (int ni = 0; ni < 4; ++ni) {
      const int row = m0 + wr + mi * 16 + fq;
      const int col = n0 + wc + ni * 16 + fr;
      f32x4 v = acc[mi][ni];
      if (EPI == 6) {
        const int seg = col >> 10, cl = col & 1023; // wave-uniform seg
        if (seg < 2) { // Q or K, row-major (b,t,h*64+k)
          u16* dst = Cb + (size_t)seg * QSZ;
#pragma unroll
          for (int r = 0; r < 4; ++r)
            dst[(size_t)(row + r) * 1024 + cl] = f2b(v[r]);
        } else { // V, per-head transposed: Vt[((b*16+h)*64+v)*T + t]
          ushort4 w;
          w.x = f2b(v[0]); w.y = f2b(v[1]); w.z = f2b(v[2]); w.w = f2b(v[3]);
          size_t vidx = 2 * QSZ +
                        (((size_t)(row >> 10) * 16 + (cl >> 6)) * 64 +
                         (cl & 63)) * (size_t)T_ + (row & 1023);
          *(ushort4*)&Cb[vidx] = w;
        }
      } else {
#pragma unroll
        for (int r = 0; r < 4; ++r) {
          float val = v[r];
          size_t idx = (size_t)(row + r) * ldc + col;
          if (EPI == 1) {
            C[idx] = val + res[idx];
          } else if (EPI == 2) {
            Cb[idx] = f2b(fmaxf(val + bias[col], 0.f));
          } else if (EPI == 3) {
            C[idx] = val + bias[col] + res[idx];
          } else if (EPI == 4) {
            C[idx] = C[idx] + val;
          }
        }
      }
    }
  }
}

// ---------------------------------------------------------------------------
// fp32 -> bf16 elementwise convert
// ---------------------------------------------------------------------------
__global__ __launch_bounds__(256) void cvt_k(const float* __restrict__ in,
                                             u16* __restrict__ out, int n4) {
  int i = blockIdx.x * 256 + threadIdx.x;
  if (i >= n4) return;
  float4 v = *(const float4*)&in[(size_t)i * 4];
  ushort4 o;
  o.x = f2b(v.x); o.y = f2b(v.y); o.z = f2b(v.z); o.w = f2b(v.w);
  *(ushort4*)&out[(size_t)i * 4] = o;
}

// ---------------------------------------------------------------------------
// transpose-convert: src (R x C) fp32 -> dst (C x R) bf16, batched over z.
// ---------------------------------------------------------------------------
__global__ __launch_bounds__(256) void tconv_k(const float* __restrict__ src,
                                               u16* __restrict__ dst, int R,
                                               int C) {
  __shared__ __align__(16) float t[32][33];
  const size_t bo = (size_t)blockIdx.z * R * C;
  const int r0 = blockIdx.y * 32, c0 = blockIdx.x * 32;
  const int tid = threadIdx.x;
  const int row = tid >> 3, c4 = (tid & 7) * 4;
  float4 v = *(const float4*)&src[bo + (size_t)(r0 + row) * C + c0 + c4];
  t[row][c4 + 0] = v.x; t[row][c4 + 1] = v.y;
  t[row][c4 + 2] = v.z; t[row][c4 + 3] = v.w;
  __syncthreads();
  ushort4 o;
  o.x = f2b(t[c4 + 0][row]); o.y = f2b(t[c4 + 1][row]);
  o.z = f2b(t[c4 + 2][row]); o.w = f2b(t[c4 + 3][row]);
  *(ushort4*)&dst[bo + (size_t)(c0 + row) * R + r0 + c4] = o;
}

// ---------------------------------------------------------------------------
// Attention pass 1 (MFMA): Lg[b,h,s] = -log2( sum_q exp(S[q,s]/8) )
// S^T tile = mfma(A=K rows(s), B=Q rows(q)); exp(S/8) = exp2(S * C_QK).
// ---------------------------------------------------------------------------
__global__ __launch_bounds__(256) void attn_lsum_k(
    const u16* __restrict__ q, const u16* __restrict__ k,
    float* __restrict__ Lg) {
  __shared__ __align__(16) u16 Qs[128 * 64]; // 16 KB, swizzled
  __shared__ float Lsh[2][128];
  const int tid = threadIdx.x, lane = tid & 63, wv = tid >> 6;
  const int s0 = blockIdx.x * 128, h = blockIdx.y, b = blockIdx.z;
  const int bh = b * H_ + h;
  const u16* qbase = q + (size_t)b * T_ * D_ + h * DK_;
  const u16* kbase = k + (size_t)b * T_ * D_ + h * DK_;

  const int wr = (wv >> 1) * 64, wc = (wv & 1) * 64;
  const int fr = lane & 15, fs8 = (lane >> 4) * 8, fq = (lane >> 4) * 4;

  bf16x8 kf[4][2];
#pragma unroll
  for (int mi = 0; mi < 4; ++mi)
#pragma unroll
    for (int ks = 0; ks < 2; ++ks)
      kf[mi][ks] = *(const bf16x8*)&kbase[(size_t)(s0 + wr + mi * 16 + fr) * D_ +
                                          ks * 32 + fs8];

  float lrun[4][4];
#pragma unroll
  for (int mi = 0; mi < 4; ++mi)
#pragma unroll
    for (int r = 0; r < 4; ++r) lrun[mi][r] = 0.f;

  const int srow = wv * 8 + (lane >> 3);
  const int sscol = ((lane & 7) ^ ((lane >> 3) & 7)) * 8;

  for (int q0 = 0; q0 < T_; q0 += 128) {
    __syncthreads();
#pragma unroll
    for (int it = 0; it < 4; ++it)
      gload16(&qbase[(size_t)(q0 + it * 32 + srow) * D_ + sscol],
              &Qs[(it * 32 + wv * 8) * 64]);
    __syncthreads();

    f32x4 acc[4][4];
#pragma unroll
    for (int mi = 0; mi < 4; ++mi)
#pragma unroll
      for (int ni = 0; ni < 4; ++ni) acc[mi][ni] = (f32x4){0.f, 0.f, 0.f, 0.f};

#pragma unroll
    for (int ks = 0; ks < 2; ++ks) {
      bf16x8 qf[4];
#pragma unroll
      for (int ni = 0; ni < 4; ++ni) {
        int qr = wc + ni * 16 + fr;
        int slot = (ks * 4 + (lane >> 4)) ^ (qr & 7);
        qf[ni] = *(const bf16x8*)&Qs[qr * 64 + slot * 8];
      }
#pragma unroll
      for (int mi = 0; mi < 4; ++mi)
#pragma unroll
        for (int ni = 0; ni < 4; ++ni)
          acc[mi][ni] = __builtin_amdgcn_mfma_f32_16x16x32_bf16(
              kf[mi][ks], qf[ni], acc[mi][ni], 0, 0, 0);
    }
#pragma unroll
    for (int mi = 0; mi < 4; ++mi)
#pragma unroll
      for (int r = 0; r < 4; ++r) {
        float e = 0.f;
#pragma unroll
        for (int ni = 0; ni < 4; ++ni) e += fexp2(acc[mi][ni][r] * C_QK);
        lrun[mi][r] += e;
      }
  }

#pragma unroll
  for (int mi = 0; mi < 4; ++mi)
#pragma unroll
    for (int r = 0; r < 4; ++r) {
      float s = lrun[mi][r];
      s += __shfl_xor(s, 1, 64); s += __shfl_xor(s, 2, 64);
      s += __shfl_xor(s, 4, 64); s += __shfl_xor(s, 8, 64);
      if (fr == 0) Lsh[wv & 1][wr + mi * 16 + fq + r] = s;
    }
  __syncthreads();
  if (tid < 128)
    Lg[(size_t)bh * T_ + s0 + tid] = -__log2f(Lsh[0][tid] + Lsh[1][tid]);
}

// ---------------------------------------------------------------------------
// Attention pass 2 (MFMA): part[q,v] = sum_s exp2(S*C_QK + Lg[s]) * V[s,v]
// ---------------------------------------------------------------------------
__global__ __launch_bounds__(256) void attn_pv_k(
    const u16* __restrict__ q, const u16* __restrict__ k,
    const u16* __restrict__ vt, const float* __restrict__ Lg,
    u16* __restrict__ part) {
  __shared__ __align__(16) u16 Ks[128 * 64];  // 16 KB swizzled
  __shared__ __align__(16) u16 Vs[64 * 128];  // 16 KB swizzled (v-major)
  __shared__ __align__(16) u16 Ps[128 * 128]; // 32 KB swizzled
  const int tid = threadIdx.x, lane = tid & 63, wv = tid >> 6;
  const int q0 = blockIdx.x * 128, h = blockIdx.y, b = blockIdx.z;
  const int bh = b * H_ + h;
  const u16* qbase = q + (size_t)b * T_ * D_ + h * DK_;
  const u16* kbase = k + (size_t)b * T_ * D_ + h * DK_;
  const u16* vtb = vt + (size_t)bh * DK_ * T_;
  const float* lb = Lg + (size_t)bh * T_;

  const int wr = (wv >> 1) * 64, wc = (wv & 1) * 64;
  const int fr = lane & 15, fs8 = (lane >> 4) * 8, fq = (lane >> 4) * 4;

  bf16x8 qf[4][2];
#pragma unroll
  for (int mi = 0; mi < 4; ++mi)
#pragma unroll
    for (int ks = 0; ks < 2; ++ks)
      qf[mi][ks] = *(const bf16x8*)&qbase[(size_t)(q0 + wr + mi * 16 + fr) * D_ +
                                          ks * 32 + fs8];

  f32x4 acc2[2][4];
#pragma unroll
  for (int i = 0; i < 2; ++i)
#pragma unroll
    for (int j = 0; j < 4; ++j) acc2[i][j] = (f32x4){0.f, 0.f, 0.f, 0.f};

  const int ksrow = wv * 8 + (lane >> 3);
  const int kscol = ((lane & 7) ^ ((lane >> 3) & 7)) * 8;

  for (int s0 = 0; s0 < T_; s0 += 128) {
    __syncthreads();
#pragma unroll
    for (int it = 0; it < 4; ++it)
      gload16(&kbase[(size_t)(s0 + it * 32 + ksrow) * D_ + kscol],
              &Ks[(it * 32 + wv * 8) * 64]);
#pragma unroll
    for (int it = 0; it < 4; ++it) {
      int v = it * 16 + wv * 4 + (lane >> 4);
      int sslot = (lane & 15) ^ (v & 7);
      gload16(&vtb[(size_t)v * T_ + s0 + sslot * 8],
              &Vs[(it * 16 + wv * 4) * 128]);
    }
    __syncthreads();

    f32x4 accs[4][4];
#pragma unroll
    for (int mi = 0; mi < 4; ++mi)
#pragma unroll
      for (int ni = 0; ni < 4; ++ni) accs[mi][ni] = (f32x4){0.f, 0.f, 0.f, 0.f};
#pragma unroll
    for (int ks = 0; ks < 2; ++ks) {
      bf16x8 kfr[4];
#pragma unroll
      for (int ni = 0; ni < 4; ++ni) {
        int sr = wc + ni * 16 + fr;
        int slot = (ks * 4 + (lane >> 4)) ^ (sr & 7);
        kfr[ni] = *(const bf16x8*)&Ks[sr * 64 + slot * 8];
      }
#pragma unroll
      for (int mi = 0; mi < 4; ++mi)
#pragma unroll
        for (int ni = 0; ni < 4; ++ni)
          accs[mi][ni] = __builtin_amdgcn_mfma_f32_16x16x32_bf16(
              qf[mi][ks], kfr[ni], accs[mi][ni], 0, 0, 0);
    }

    // P = exp2(S*C_QK + lg[s]) -> Ps (swizzled scalar writes)
#pragma unroll
    for (int ni = 0; ni < 4; ++ni) {
      float lg = lb[s0 + wc + ni * 16 + fr];
      int scol = wc + ni * 16 + fr;
#pragma unroll
      for (int mi = 0; mi < 4; ++mi) {
#pragma unroll
        for (int r = 0; r < 4; ++r) {
          int qrow = wr + mi * 16 + fq + r;
          u16 pv = f2b(fexp2(fmaf(accs[mi][ni][r], C_QK, lg)));
          int eoff = qrow * 128 + ((((scol << 1) ^ ((qrow & 7) << 4))) >> 1);
          Ps[eoff] = pv;
        }
      }
    }
    __syncthreads();

#pragma unroll
    for (int ks2 = 0; ks2 < 4; ++ks2) {
      bf16x8 pa[2], vb2[4];
#pragma unroll
      for (int mi2 = 0; mi2 < 2; ++mi2) {
        int qr = wv * 32 + mi2 * 16 + fr;
        int slot = (ks2 * 4 + (lane >> 4)) ^ (qr & 7);
        pa[mi2] = *(const bf16x8*)&Ps[qr * 128 + slot * 8];
      }
#pragma unroll
      for (int ni2 = 0; ni2 < 4; ++ni2) {
        int v = ni2 * 16 + fr;
        int slot = (ks2 * 4 + (lane >> 4)) ^ (v & 7);
        vb2[ni2] = *(const bf16x8*)&Vs[v * 128 + slot * 8];
      }
#pragma unroll
      for (int mi2 = 0; mi2 < 2; ++mi2)
#pragma unroll
        for (int ni2 = 0; ni2 < 4; ++ni2)
          acc2[mi2][ni2] = __builtin_amdgcn_mfma_f32_16x16x32_bf16(
              pa[mi2], vb2[ni2], acc2[mi2][ni2], 0, 0, 0);
    }
  }

#pragma unroll
  for (int mi2 = 0; mi2 < 2; ++mi2)
#pragma unroll
    for (int ni2 = 0; ni2 < 4; ++ni2)
#pragma unroll
      for (int r = 0; r < 4; ++r) {
        int qrow = q0 + wv * 32 + mi2 * 16 + fq + r;
        int v = ni2 * 16 + fr;
        part[(size_t)(b * T_ + qrow) * D_ + h * DK_ + v] =
            f2b(acc2[mi2][ni2][r]);
      }
}

// ---------------------------------------------------------------------------
// Pseudo-norm: y - mean(y) - std(y, ddof=1) per row of 1024. In-place safe.
// ---------------------------------------------------------------------------
template <bool WB>
__global__ __launch_bounds__(256) void norm_k(const float* __restrict__ in,
                                              float* __restrict__ out,
                                              u16* __restrict__ ob) {
  __shared__ float red[8];
  const int row = blockIdx.x, tid = threadIdx.x;
  float4 vv = *(const float4*)&in[(size_t)row * D_ + tid * 4];
  float s = vv.x + vv.y + vv.z + vv.w;
  for (int off = 1; off < 64; off <<= 1) s += __shfl_xor(s, off, 64);
  if ((tid & 63) == 0) red[tid >> 6] = s;
  __syncthreads();
  float mean = (red[0] + red[1] + red[2] + red[3]) * (1.f / 1024.f);
  float dx = vv.x - mean, dy = vv.y - mean, dz = vv.z - mean, dw = vv.w - mean;
  float s2 = dx * dx + dy * dy + dz * dz + dw * dw;
  __syncthreads();
  for (int off = 1; off < 64; off <<= 1) s2 += __shfl_xor(s2, off, 64);
  if ((tid & 63) == 0) red[4 + (tid >> 6)] = s2;
  __syncthreads();
  float var = (red[4] + red[5] + red[6] + red[7]) * (1.f / 1023.f);
  float sd = sqrtf(var);
  float4 o = {dx - sd, dy - sd, dz - sd, dw - sd};
  *(float4*)&out[(size_t)row * D_ + tid * 4] = o;
  if (WB) {
    ushort4 q;
    q.x = f2b(o.x); q.y = f2b(o.y); q.z = f2b(o.z); q.w = f2b(o.w);
    *(ushort4*)&ob[(size_t)row * D_ + tid * 4] = q;
  }
}

// ---------------------------------------------------------------------------
extern "C" void kernel_launch(void* const* d_in, const int* in_sizes, int n_in,
                              void* d_out, int out_size, void* d_ws,
                              size_t ws_size, hipStream_t stream) {
  const float* x  = (const float*)d_in[0];
  const float* Wq = (const float*)d_in[1];
  const float* Wk = (const float*)d_in[2];
  const float* Wv = (const float*)d_in[3];
  const float* Wo = (const float*)d_in[4];
  const float* W1 = (const float*)d_in[5];
  const float* b1 = (const float*)d_in[6];
  const float* W2 = (const float*)d_in[7];
  const float* b2 = (const float*)d_in[8];

  char* w = (char*)d_ws;
  u16* qb16   = (u16*)(w + (0ull << 20));  // +QSZ: kb16, +2*QSZ: Vt
  u16* kb16   = (u16*)(w + (16ull << 20));
  u16* Vt     = (u16*)(w + (32ull << 20));
  u16* xb     = (u16*)(w + (48ull << 20));
  u16* part16 = (u16*)(w + (64ull << 20));
  u16* Wqkv   = (u16*)(w + (80ull << 20)); // 3072 x 1024 Bt (Wq|Wk|Wv)
  u16* Wot    = (u16*)(w + (86ull << 20));
  u16* W1b    = (u16*)(w + (88ull << 20));
  u16* W2b    = (u16*)(w + (96ull << 20));
  float* Lg   = (float*)(w + (104ull << 20));
  u16* o1b = qb16;            // after attention
  u16* hc  = kb16;            // 32 MB ([16,48M)) after attention
  float* o1 = (float*)d_out;

  dim3 thr(256);

  // ---- convert weights/activations to bf16 (Bt layout = N x K) ----
  int n4x = (M_ * D_) / 4;
  cvt_k<<<dim3((n4x + 255) / 256), thr, 0, stream>>>(x, xb, n4x);
  tconv_k<<<dim3(2, 32, 16), thr, 0, stream>>>(Wq, Wqkv, 1024, 64);
  tconv_k<<<dim3(2, 32, 16), thr, 0, stream>>>(Wk, Wqkv + 1048576, 1024, 64);
  tconv_k<<<dim3(2, 32, 16), thr, 0, stream>>>(Wv, Wqkv + 2097152, 1024, 64);
  tconv_k<<<dim3(32, 32, 1), thr, 0, stream>>>(Wo, Wot, 1024, 1024);
  int n4w = (FF_ * D_) / 4;
  cvt_k<<<dim3((n4w + 255) / 256), thr, 0, stream>>>(W1, W1b, n4w);
  cvt_k<<<dim3((n4w + 255) / 256), thr, 0, stream>>>(W2, W2b, n4w);

  // ---- fused QKV projection (N=3072; epilogue splits Q/K row-major, V^T) --
  gemm16_k<6><<<dim3(3072 / 128, M_ / 128), thr, 0, stream>>>(
      xb, Wqkv, M_, 3072, D_, D_, D_, nullptr, D_, qb16, nullptr, nullptr);

  // ---- attention (query-axis softmax, no-max two-pass, MFMA) ----
  dim3 ga(T_ / 128, H_, B_);
  attn_lsum_k<<<ga, thr, 0, stream>>>(qb16, kb16, Lg);
  attn_pv_k<<<ga, thr, 0, stream>>>(qb16, kb16, Vt, Lg, part16);

  // ---- out1 = part @ Wo + x -> d_out (fp32); pseudo-norm + bf16 copy ----
  gemm16_k<1><<<dim3(D_ / 128, M_ / 128), thr, 0, stream>>>(
      part16, Wot, M_, D_, D_, D_, D_, o1, D_, nullptr, x, nullptr);
  norm_k<true><<<dim3(M_), thr, 0, stream>>>(o1, o1, o1b);

  // ---- FF in 2 inner-dim chunks of 2048 ----
  for (int c = 0; c < 2; ++c) {
    const u16* W1c = W1b + (size_t)c * 2048 * 1024;
    const u16* W2c = W2b + (size_t)c * 2048;
    gemm16_k<2><<<dim3(2048 / 128, M_ / 128), thr, 0, stream>>>(
        o1b, W1c, M_, 2048, 1024, 1024, 1024, nullptr, 2048, hc, nullptr,
        b1 + c * 2048);
    if (c == 0) {
      gemm16_k<3><<<dim3(D_ / 128, M_ / 128), thr, 0, stream>>>(
          hc, W2c, M_, 1024, 2048, 2048, FF_, o1, D_, nullptr, o1, b2);
    } else {
      gemm16_k<4><<<dim3(D_ / 128, M_ / 128), thr, 0, stream>>>(
          hc, W2c, M_, 1024, 2048, 2048, FF_, o1, D_, nullptr, nullptr, nullptr);
    }
  }

  // ---- final pseudo-norm in place on d_out ----
  norm_k<false><<<dim3(M_), thr, 0, stream>>>(o1, o1, nullptr);
}

// Round 8
// 613.300 us; speedup vs baseline: 6.4396x; 1.0585x over previous
//
#include <hip/hip_runtime.h>
#include <hip/hip_bf16.h>
#include <math.h>

// Encoder block. B=8, T=1024, D=1024, H=16, dk=dv=64, FF=4096.
// softmax in reference is over the QUERY axis (axis=2 of (B,H,Tq,Ts)).
// Round 8 == Round 6 kernel (two infra failures; never executed).
// attn_pv restructured: S^T = mfma(K,Q) so each lane holds 4 consecutive s
// per q; P written as packed 8B stores; V pre-scaled by 1/l (vscale_k) so
// the P inner loop is exp2(S*C) only; f2b via __float2bfloat16 (HW cvt).
//
// Workspace (~105 MB):
//  [0,16M)  qb16 -> o1b16 after attention
//  [16,32M) kb16 --\ hc (32 MB, FF hidden chunk) after attention
//  [32,48M) Vt ----/  (b,h,v,s bf16; pre-scaled by rl after lsum)
//  [48,64M) xb16 (dead after QKV)   [64,80M) part16 (dead after Wo GEMM)
//  [80,86M) Wqkv (3072 x 1024 Bt)  [86,88M) Wot
//  [88,96M) W1b  [96,104M) W2b   [104M..) Lrcp (1/l, fp32, B*H*T)

#define B_ 8
#define T_ 1024
#define D_ 1024
#define H_ 16
#define DK_ 64
#define FF_ 4096
#define M_ (B_ * T_) // 8192

typedef unsigned short u16;
typedef __attribute__((ext_vector_type(8))) short bf16x8;
typedef __attribute__((ext_vector_type(4))) float f32x4;

#define QSZ 8388608ull // 8192*1024 elements (16 MB bf16)

__device__ __forceinline__ float b2f(u16 u) {
  union { unsigned int i; float f; } x;
  x.i = ((unsigned int)u) << 16;
  return x.f;
}
__device__ __forceinline__ u16 f2b(float f) {
  __hip_bfloat16 h = __float2bfloat16(f); // RNE, single HW op on gfx950
  return *(u16*)&h;
}
__device__ __forceinline__ float fexp2(float x) {
#if __has_builtin(__builtin_amdgcn_exp2f)
  return __builtin_amdgcn_exp2f(x);
#else
  return exp2f(x);
#endif
}
#define C_QK 0.1803368801111244f // 0.125 * log2(e)

typedef __attribute__((address_space(1))) const void gas_void;
typedef __attribute__((address_space(3))) void las_void;
__device__ __forceinline__ void gload16(const void* g, void* l) {
  __builtin_amdgcn_global_load_lds((gas_void*)g, (las_void*)l, 16, 0, 0);
}

// ---------------------------------------------------------------------------
// bf16 MFMA GEMM, 2-phase double-buffered. C[M,N] = A[M,K] @ Bt[N,K]^T
// EPI: 1: C=acc+res   2: Cb=bf16(relu(acc+bias))   3: C=acc+bias+res
//      4: C+=acc      6: fused-QKV split (Cb base = qb16; +QSZ k; +2QSZ Vt)
// ---------------------------------------------------------------------------
template <int EPI>
__global__ __launch_bounds__(256) void gemm16_k(
    const u16* __restrict__ A, const u16* __restrict__ Bt,
    int M, int N, int K, int lda, int ldb,
    float* __restrict__ C, int ldc, u16* __restrict__ Cb,
    const float* __restrict__ res, const float* __restrict__ bias) {
  __shared__ __align__(16) u16 As[2][128 * 32]; // 2 x 8 KB
  __shared__ __align__(16) u16 Bs[2][128 * 32];

  const int tid = threadIdx.x;
  const int lane = tid & 63, wv = tid >> 6;
  const int m0 = blockIdx.y * 128, n0 = blockIdx.x * 128;
  const int wr = (wv >> 1) * 64, wc = (wv & 1) * 64;

  f32x4 acc[4][4];
#pragma unroll
  for (int i = 0; i < 4; ++i)
#pragma unroll
    for (int j = 0; j < 4; ++j) acc[i][j] = (f32x4){0.f, 0.f, 0.f, 0.f};

  const int srow = wv * 16 + (lane >> 2);
  const int scol = (lane & 3) * 8;
  const int fr = lane & 15, fk = (lane >> 4) * 8;

  const u16* gA0 = &A[(size_t)(m0 + srow) * lda + scol];
  const u16* gA1 = &A[(size_t)(m0 + srow + 64) * lda + scol];
  const u16* gB0 = &Bt[(size_t)(n0 + srow) * ldb + scol];
  const u16* gB1 = &Bt[(size_t)(n0 + srow + 64) * ldb + scol];

  gload16(gA0, &As[0][wv * 512]);
  gload16(gA1, &As[0][2048 + wv * 512]);
  gload16(gB0, &Bs[0][wv * 512]);
  gload16(gB1, &Bs[0][2048 + wv * 512]);
  __syncthreads();

  int cur = 0;
  for (int k0 = 0; k0 < K; k0 += 32) {
    if (k0 + 32 < K) {
      int nx = cur ^ 1, ko = k0 + 32;
      gload16(gA0 + ko, &As[nx][wv * 512]);
      gload16(gA1 + ko, &As[nx][2048 + wv * 512]);
      gload16(gB0 + ko, &Bs[nx][wv * 512]);
      gload16(gB1 + ko, &Bs[nx][2048 + wv * 512]);
    }
    bf16x8 af[4], bfr[4];
#pragma unroll
    for (int mi = 0; mi < 4; ++mi)
      af[mi] = *(const bf16x8*)&As[cur][(wr + mi * 16 + fr) * 32 + fk];
#pragma unroll
    for (int ni = 0; ni < 4; ++ni)
      bfr[ni] = *(const bf16x8*)&Bs[cur][(wc + ni * 16 + fr) * 32 + fk];
#pragma unroll
    for (int mi = 0; mi < 4; ++mi)
#pragma unroll
      for (int ni = 0; ni < 4; ++ni)
        acc[mi][ni] = __builtin_amdgcn_mfma_f32_16x16x32_bf16(
            af[mi], bfr[ni], acc[mi][ni], 0, 0, 0);
    __syncthreads();
    cur ^= 1;
  }

  const int fq = (lane >> 4) * 4;
#pragma unroll
  for (int mi = 0; mi < 4; ++mi) {
#pragma unroll
    for (int ni = 0; ni < 4; ++ni) {
      const int row = m0 + wr + mi * 16 + fq;
      const int col = n0 + wc + ni * 16 + fr;
      f32x4 v = acc[mi][ni];
      if (EPI == 6) {
        const int seg = col >> 10, cl = col & 1023; // wave-uniform seg
        if (seg < 2) { // Q or K, row-major (b,t,h*64+k)
          u16* dst = Cb + (size_t)seg * QSZ;
#pragma unroll
          for (int r = 0; r < 4; ++r)
            dst[(size_t)(row + r) * 1024 + cl] = f2b(v[r]);
        } else { // V, per-head transposed: Vt[((b*16+h)*64+v)*T + t]
          ushort4 w;
          w.x = f2b(v[0]); w.y = f2b(v[1]); w.z = f2b(v[2]); w.w = f2b(v[3]);
          size_t vidx = 2 * QSZ +
                        (((size_t)(row >> 10) * 16 + (cl >> 6)) * 64 +
                         (cl & 63)) * (size_t)T_ + (row & 1023);
          *(ushort4*)&Cb[vidx] = w;
        }
      } else {
#pragma unroll
        for (int r = 0; r < 4; ++r) {
          float val = v[r];
          size_t idx = (size_t)(row + r) * ldc + col;
          if (EPI == 1) {
            C[idx] = val + res[idx];
          } else if (EPI == 2) {
            Cb[idx] = f2b(fmaxf(val + bias[col], 0.f));
          } else if (EPI == 3) {
            C[idx] = val + bias[col] + res[idx];
          } else if (EPI == 4) {
            C[idx] = C[idx] + val;
          }
        }
      }
    }
  }
}

// ---------------------------------------------------------------------------
// fp32 -> bf16 elementwise convert
// ---------------------------------------------------------------------------
__global__ __launch_bounds__(256) void cvt_k(const float* __restrict__ in,
                                             u16* __restrict__ out, int n4) {
  int i = blockIdx.x * 256 + threadIdx.x;
  if (i >= n4) return;
  float4 v = *(const float4*)&in[(size_t)i * 4];
  ushort4 o;
  o.x = f2b(v.x); o.y = f2b(v.y); o.z = f2b(v.z); o.w = f2b(v.w);
  *(ushort4*)&out[(size_t)i * 4] = o;
}

// ---------------------------------------------------------------------------
// transpose-convert: src (R x C) fp32 -> dst (C x R) bf16, batched over z.
// ---------------------------------------------------------------------------
__global__ __launch_bounds__(256) void tconv_k(const float* __restrict__ src,
                                               u16* __restrict__ dst, int R,
                                               int C) {
  __shared__ __align__(16) float t[32][33];
  const size_t bo = (size_t)blockIdx.z * R * C;
  const int r0 = blockIdx.y * 32, c0 = blockIdx.x * 32;
  const int tid = threadIdx.x;
  const int row = tid >> 3, c4 = (tid & 7) * 4;
  float4 v = *(const float4*)&src[bo + (size_t)(r0 + row) * C + c0 + c4];
  t[row][c4 + 0] = v.x; t[row][c4 + 1] = v.y;
  t[row][c4 + 2] = v.z; t[row][c4 + 3] = v.w;
  __syncthreads();
  ushort4 o;
  o.x = f2b(t[c4 + 0][row]); o.y = f2b(t[c4 + 1][row]);
  o.z = f2b(t[c4 + 2][row]); o.w = f2b(t[c4 + 3][row]);
  *(ushort4*)&dst[bo + (size_t)(c0 + row) * R + r0 + c4] = o;
}

// ---------------------------------------------------------------------------
// Attention pass 1 (MFMA): Lrcp[b,h,s] = 1 / sum_q exp(S[q,s]/8)
// S^T tile = mfma(A=K rows(s), B=Q rows(q)); exp(S/8) = exp2(S * C_QK).
// ---------------------------------------------------------------------------
__global__ __launch_bounds__(256) void attn_lsum_k(
    const u16* __restrict__ q, const u16* __restrict__ k,
    float* __restrict__ Lrcp) {
  __shared__ __align__(16) u16 Qs[128 * 64]; // 16 KB, swizzled
  __shared__ float Lsh[2][128];
  const int tid = threadIdx.x, lane = tid & 63, wv = tid >> 6;
  const int s0 = blockIdx.x * 128, h = blockIdx.y, b = blockIdx.z;
  const int bh = b * H_ + h;
  const u16* qbase = q + (size_t)b * T_ * D_ + h * DK_;
  const u16* kbase = k + (size_t)b * T_ * D_ + h * DK_;

  const int wr = (wv >> 1) * 64, wc = (wv & 1) * 64;
  const int fr = lane & 15, fs8 = (lane >> 4) * 8, fq = (lane >> 4) * 4;

  bf16x8 kf[4][2];
#pragma unroll
  for (int mi = 0; mi < 4; ++mi)
#pragma unroll
    for (int ks = 0; ks < 2; ++ks)
      kf[mi][ks] = *(const bf16x8*)&kbase[(size_t)(s0 + wr + mi * 16 + fr) * D_ +
                                          ks * 32 + fs8];

  float lrun[4][4];
#pragma unroll
  for (int mi = 0; mi < 4; ++mi)
#pragma unroll
    for (int r = 0; r < 4; ++r) lrun[mi][r] = 0.f;

  const int srow = wv * 8 + (lane >> 3);
  const int sscol = ((lane & 7) ^ ((lane >> 3) & 7)) * 8;

  for (int q0 = 0; q0 < T_; q0 += 128) {
    __syncthreads();
#pragma unroll
    for (int it = 0; it < 4; ++it)
      gload16(&qbase[(size_t)(q0 + it * 32 + srow) * D_ + sscol],
              &Qs[(it * 32 + wv * 8) * 64]);
    __syncthreads();

    f32x4 acc[4][4];
#pragma unroll
    for (int mi = 0; mi < 4; ++mi)
#pragma unroll
      for (int ni = 0; ni < 4; ++ni) acc[mi][ni] = (f32x4){0.f, 0.f, 0.f, 0.f};

#pragma unroll
    for (int ks = 0; ks < 2; ++ks) {
      bf16x8 qf[4];
#pragma unroll
      for (int ni = 0; ni < 4; ++ni) {
        int qr = wc + ni * 16 + fr;
        int slot = (ks * 4 + (lane >> 4)) ^ (qr & 7);
        qf[ni] = *(const bf16x8*)&Qs[qr * 64 + slot * 8];
      }
#pragma unroll
      for (int mi = 0; mi < 4; ++mi)
#pragma unroll
        for (int ni = 0; ni < 4; ++ni)
          acc[mi][ni] = __builtin_amdgcn_mfma_f32_16x16x32_bf16(
              kf[mi][ks], qf[ni], acc[mi][ni], 0, 0, 0);
    }
#pragma unroll
    for (int mi = 0; mi < 4; ++mi)
#pragma unroll
      for (int r = 0; r < 4; ++r) {
        float e = 0.f;
#pragma unroll
        for (int ni = 0; ni < 4; ++ni) e += fexp2(acc[mi][ni][r] * C_QK);
        lrun[mi][r] += e;
      }
  }

#pragma unroll
  for (int mi = 0; mi < 4; ++mi)
#pragma unroll
    for (int r = 0; r < 4; ++r) {
      float s = lrun[mi][r];
      s += __shfl_xor(s, 1, 64); s += __shfl_xor(s, 2, 64);
      s += __shfl_xor(s, 4, 64); s += __shfl_xor(s, 8, 64);
      if (fr == 0) Lsh[wv & 1][wr + mi * 16 + fq + r] = s;
    }
  __syncthreads();
  if (tid < 128)
    Lrcp[(size_t)bh * T_ + s0 + tid] = 1.f / (Lsh[0][tid] + Lsh[1][tid]);
}

// ---------------------------------------------------------------------------
// V pre-scale: Vt[(bh*64+v)*1024 + s] *= Lrcp[bh*1024 + s]  (8 u16/thread)
// ---------------------------------------------------------------------------
__global__ __launch_bounds__(256) void vscale_k(u16* __restrict__ vt,
                                                const float* __restrict__ Lrcp) {
  int i8 = blockIdx.x * 256 + threadIdx.x;
  size_t base = (size_t)i8 * 8;
  int bh = (int)(base >> 16);      // 64 v-rows * 1024 s per bh
  int s = (int)(base & 1023);
  float4 r0 = *(const float4*)&Lrcp[(size_t)bh * 1024 + s];
  float4 r1 = *(const float4*)&Lrcp[(size_t)bh * 1024 + s + 4];
  ushort4 a = *(const ushort4*)&vt[base];
  ushort4 c = *(const ushort4*)&vt[base + 4];
  ushort4 oa, oc;
  oa.x = f2b(b2f(a.x) * r0.x); oa.y = f2b(b2f(a.y) * r0.y);
  oa.z = f2b(b2f(a.z) * r0.z); oa.w = f2b(b2f(a.w) * r0.w);
  oc.x = f2b(b2f(c.x) * r1.x); oc.y = f2b(b2f(c.y) * r1.y);
  oc.z = f2b(b2f(c.z) * r1.z); oc.w = f2b(b2f(c.w) * r1.w);
  *(ushort4*)&vt[base] = oa;
  *(ushort4*)&vt[base + 4] = oc;
}

// ---------------------------------------------------------------------------
// Attention pass 2 (MFMA): part[q,v] = sum_s exp2(S[q,s]*C_QK) * V'[s,v]
// S^T = mfma(K,Q): lane holds q=wc+ni*16+fr (col), s=wr+mi*16+fq+r (row)
// -> P packed 8B writes into Ps[q][s] with byte ^= (q&15)<<4 swizzle.
// ---------------------------------------------------------------------------
__global__ __launch_bounds__(256) void attn_pv_k(
    const u16* __restrict__ q, const u16* __restrict__ k,
    const u16* __restrict__ vt, u16* __restrict__ part) {
  __shared__ __align__(16) u16 Ks[128 * 64];  // 16 KB swizzled
  __shared__ __align__(16) u16 Vs[64 * 128];  // 16 KB swizzled (v-major)
  __shared__ __align__(16) u16 Ps[128 * 128]; // 32 KB [q][s], ^(q&15)<<4
  const int tid = threadIdx.x, lane = tid & 63, wv = tid >> 6;
  const int q0 = blockIdx.x * 128, h = blockIdx.y, b = blockIdx.z;
  const int bh = b * H_ + h;
  const u16* qbase = q + (size_t)b * T_ * D_ + h * DK_;
  const u16* kbase = k + (size_t)b * T_ * D_ + h * DK_;
  const u16* vtb = vt + (size_t)bh * DK_ * T_;

  const int wr = (wv >> 1) * 64, wc = (wv & 1) * 64; // S^T quadrant: s, q
  const int fr = lane & 15, fs8 = (lane >> 4) * 8, fq = (lane >> 4) * 4;

  // Q fragments (B-operand of S^T): rows q = q0 + wc + ni*16 + fr
  bf16x8 qf[4][2];
#pragma unroll
  for (int ni = 0; ni < 4; ++ni)
#pragma unroll
    for (int ks = 0; ks < 2; ++ks)
      qf[ni][ks] = *(const bf16x8*)&qbase[(size_t)(q0 + wc + ni * 16 + fr) * D_ +
                                          ks * 32 + fs8];

  f32x4 acc2[2][4]; // PV out: rows q0 + wv*32 + mi2*16, cols ni2*16
#pragma unroll
  for (int i = 0; i < 2; ++i)
#pragma unroll
    for (int j = 0; j < 4; ++j) acc2[i][j] = (f32x4){0.f, 0.f, 0.f, 0.f};

  const int ksrow = wv * 8 + (lane >> 3);
  const int kscol = ((lane & 7) ^ ((lane >> 3) & 7)) * 8;

  for (int s0 = 0; s0 < T_; s0 += 128) {
    __syncthreads(); // prev-iter Ks/Vs/Ps reads done
#pragma unroll
    for (int it = 0; it < 4; ++it)
      gload16(&kbase[(size_t)(s0 + it * 32 + ksrow) * D_ + kscol],
              &Ks[(it * 32 + wv * 8) * 64]);
#pragma unroll
    for (int it = 0; it < 4; ++it) {
      int v = it * 16 + wv * 4 + (lane >> 4);
      int sslot = (lane & 15) ^ (v & 7);
      gload16(&vtb[(size_t)v * T_ + s0 + sslot * 8],
              &Vs[(it * 16 + wv * 4) * 128]);
    }
    __syncthreads();

    // S^T quadrant: A = K rows (s), B = Q rows (q)
    f32x4 st[4][4];
#pragma unroll
    for (int mi = 0; mi < 4; ++mi)
#pragma unroll
      for (int ni = 0; ni < 4; ++ni) st[mi][ni] = (f32x4){0.f, 0.f, 0.f, 0.f};
#pragma unroll
    for (int ks = 0; ks < 2; ++ks) {
      bf16x8 kfa[4];
#pragma unroll
      for (int mi = 0; mi < 4; ++mi) {
        int sr = wr + mi * 16 + fr;
        int slot = (ks * 4 + (lane >> 4)) ^ (sr & 7);
        kfa[mi] = *(const bf16x8*)&Ks[sr * 64 + slot * 8];
      }
#pragma unroll
      for (int mi = 0; mi < 4; ++mi)
#pragma unroll
        for (int ni = 0; ni < 4; ++ni)
          st[mi][ni] = __builtin_amdgcn_mfma_f32_16x16x32_bf16(
              kfa[mi], qf[ni][ks], st[mi][ni], 0, 0, 0);
    }

    // P = exp2(S*C_QK) -> Ps[q][s], packed 8B (4 consecutive s per lane)
#pragma unroll
    for (int ni = 0; ni < 4; ++ni) {
      int qcol = wc + ni * 16 + fr;
#pragma unroll
      for (int mi = 0; mi < 4; ++mi) {
        int sb = wr + mi * 16 + fq; // 4 consecutive s, 8B aligned
        u16 e0 = f2b(fexp2(st[mi][ni][0] * C_QK));
        u16 e1 = f2b(fexp2(st[mi][ni][1] * C_QK));
        u16 e2 = f2b(fexp2(st[mi][ni][2] * C_QK));
        u16 e3 = f2b(fexp2(st[mi][ni][3] * C_QK));
        uint2 w;
        w.x = (unsigned int)e0 | ((unsigned int)e1 << 16);
        w.y = (unsigned int)e2 | ((unsigned int)e3 << 16);
        int byte = qcol * 256 + ((sb * 2) ^ ((qcol & 15) << 4));
        *(uint2*)((char*)Ps + byte) = w;
      }
    }
    __syncthreads();

    // acc2 += P(rows wv*32..+32) @ V'
#pragma unroll
    for (int ks2 = 0; ks2 < 4; ++ks2) {
      bf16x8 pa[2], vb2[4];
#pragma unroll
      for (int mi2 = 0; mi2 < 2; ++mi2) {
        int qr = wv * 32 + mi2 * 16 + fr;
        int byte = qr * 256 + (((ks2 * 32 + (lane >> 4) * 8) * 2) ^ ((qr & 15) << 4));
        pa[mi2] = *(const bf16x8*)((const char*)Ps + byte);
      }
#pragma unroll
      for (int ni2 = 0; ni2 < 4; ++ni2) {
        int v = ni2 * 16 + fr;
        int slot = (ks2 * 4 + (lane >> 4)) ^ (v & 7);
        vb2[ni2] = *(const bf16x8*)&Vs[v * 128 + slot * 8];
      }
#pragma unroll
      for (int mi2 = 0; mi2 < 2; ++mi2)
#pragma unroll
        for (int ni2 = 0; ni2 < 4; ++ni2)
          acc2[mi2][ni2] = __builtin_amdgcn_mfma_f32_16x16x32_bf16(
              pa[mi2], vb2[ni2], acc2[mi2][ni2], 0, 0, 0);
    }
  }

#pragma unroll
  for (int mi2 = 0; mi2 < 2; ++mi2)
#pragma unroll
    for (int ni2 = 0; ni2 < 4; ++ni2)
#pragma unroll
      for (int r = 0; r < 4; ++r) {
        int qrow = q0 + wv * 32 + mi2 * 16 + fq + r;
        int v = ni2 * 16 + fr;
        part[(size_t)(b * T_ + qrow) * D_ + h * DK_ + v] =
            f2b(acc2[mi2][ni2][r]);
      }
}

// ---------------------------------------------------------------------------
// Pseudo-norm: y - mean(y) - std(y, ddof=1) per row of 1024. In-place safe.
// ---------------------------------------------------------------------------
template <bool WB>
__global__ __launch_bounds__(256) void norm_k(const float* __restrict__ in,
                                              float* __restrict__ out,
                                              u16* __restrict__ ob) {
  __shared__ float red[8];
  const int row = blockIdx.x, tid = threadIdx.x;
  float4 vv = *(const float4*)&in[(size_t)row * D_ + tid * 4];
  float s = vv.x + vv.y + vv.z + vv.w;
  for (int off = 1; off < 64; off <<= 1) s += __shfl_xor(s, off, 64);
  if ((tid & 63) == 0) red[tid >> 6] = s;
  __syncthreads();
  float mean = (red[0] + red[1] + red[2] + red[3]) * (1.f / 1024.f);
  float dx = vv.x - mean, dy = vv.y - mean, dz = vv.z - mean, dw = vv.w - mean;
  float s2 = dx * dx + dy * dy + dz * dz + dw * dw;
  __syncthreads();
  for (int off = 1; off < 64; off <<= 1) s2 += __shfl_xor(s2, off, 64);
  if ((tid & 63) == 0) red[4 + (tid >> 6)] = s2;
  __syncthreads();
  float var = (red[4] + red[5] + red[6] + red[7]) * (1.f / 1023.f);
  float sd = sqrtf(var);
  float4 o = {dx - sd, dy - sd, dz - sd, dw - sd};
  *(float4*)&out[(size_t)row * D_ + tid * 4] = o;
  if (WB) {
    ushort4 q;
    q.x = f2b(o.x); q.y = f2b(o.y); q.z = f2b(o.z); q.w = f2b(o.w);
    *(ushort4*)&ob[(size_t)row * D_ + tid * 4] = q;
  }
}

// ---------------------------------------------------------------------------
extern "C" void kernel_launch(void* const* d_in, const int* in_sizes, int n_in,
                              void* d_out, int out_size, void* d_ws,
                              size_t ws_size, hipStream_t stream) {
  const float* x  = (const float*)d_in[0];
  const float* Wq = (const float*)d_in[1];
  const float* Wk = (const float*)d_in[2];
  const float* Wv = (const float*)d_in[3];
  const float* Wo = (const float*)d_in[4];
  const float* W1 = (const float*)d_in[5];
  const float* b1 = (const float*)d_in[6];
  const float* W2 = (const float*)d_in[7];
  const float* b2 = (const float*)d_in[8];

  char* w = (char*)d_ws;
  u16* qb16   = (u16*)(w + (0ull << 20));  // +QSZ: kb16, +2*QSZ: Vt
  u16* kb16   = (u16*)(w + (16ull << 20));
  u16* Vt     = (u16*)(w + (32ull << 20));
  u16* xb     = (u16*)(w + (48ull << 20));
  u16* part16 = (u16*)(w + (64ull << 20));
  u16* Wqkv   = (u16*)(w + (80ull << 20)); // 3072 x 1024 Bt (Wq|Wk|Wv)
  u16* Wot    = (u16*)(w + (86ull << 20));
  u16* W1b    = (u16*)(w + (88ull << 20));
  u16* W2b    = (u16*)(w + (96ull << 20));
  float* Lrcp = (float*)(w + (104ull << 20));
  u16* o1b = qb16;            // after attention
  u16* hc  = kb16;            // 32 MB ([16,48M)) after attention
  float* o1 = (float*)d_out;

  dim3 thr(256);

  // ---- convert weights/activations to bf16 (Bt layout = N x K) ----
  int n4x = (M_ * D_) / 4;
  cvt_k<<<dim3((n4x + 255) / 256), thr, 0, stream>>>(x, xb, n4x);
  tconv_k<<<dim3(2, 32, 16), thr, 0, stream>>>(Wq, Wqkv, 1024, 64);
  tconv_k<<<dim3(2, 32, 16), thr, 0, stream>>>(Wk, Wqkv + 1048576, 1024, 64);
  tconv_k<<<dim3(2, 32, 16), thr, 0, stream>>>(Wv, Wqkv + 2097152, 1024, 64);
  tconv_k<<<dim3(32, 32, 1), thr, 0, stream>>>(Wo, Wot, 1024, 1024);
  int n4w = (FF_ * D_) / 4;
  cvt_k<<<dim3((n4w + 255) / 256), thr, 0, stream>>>(W1, W1b, n4w);
  cvt_k<<<dim3((n4w + 255) / 256), thr, 0, stream>>>(W2, W2b, n4w);

  // ---- fused QKV projection (N=3072; epilogue splits Q/K row-major, V^T) --
  gemm16_k<6><<<dim3(3072 / 128, M_ / 128), thr, 0, stream>>>(
      xb, Wqkv, M_, 3072, D_, D_, D_, nullptr, D_, qb16, nullptr, nullptr);

  // ---- attention (query-axis softmax, no-max two-pass, MFMA) ----
  dim3 ga(T_ / 128, H_, B_);
  attn_lsum_k<<<ga, thr, 0, stream>>>(qb16, kb16, Lrcp);
  vscale_k<<<dim3((int)(QSZ / 8 / 256)), thr, 0, stream>>>(Vt, Lrcp);
  attn_pv_k<<<ga, thr, 0, stream>>>(qb16, kb16, Vt, part16);

  // ---- out1 = part @ Wo + x -> d_out (fp32); pseudo-norm + bf16 copy ----
  gemm16_k<1><<<dim3(D_ / 128, M_ / 128), thr, 0, stream>>>(
      part16, Wot, M_, D_, D_, D_, D_, o1, D_, nullptr, x, nullptr);
  norm_k<true><<<dim3(M_), thr, 0, stream>>>(o1, o1, o1b);

  // ---- FF in 2 inner-dim chunks of 2048 ----
  for (int c = 0; c < 2; ++c) {
    const u16* W1c = W1b + (size_t)c * 2048 * 1024;
    const u16* W2c = W2b + (size_t)c * 2048;
    gemm16_k<2><<<dim3(2048 / 128, M_ / 128), thr, 0, stream>>>(
        o1b, W1c, M_, 2048, 1024, 1024, 1024, nullptr, 2048, hc, nullptr,
        b1 + c * 2048);
    if (c == 0) {
      gemm16_k<3><<<dim3(D_ / 128, M_ / 128), thr, 0, stream>>>(
          hc, W2c, M_, 1024, 2048, 2048, FF_, o1, D_, nullptr, o1, b2);
    } else {
      gemm16_k<4><<<dim3(D_ / 128, M_ / 128), thr, 0, stream>>>(
          hc, W2c, M_, 1024, 2048, 2048, FF_, o1, D_, nullptr, nullptr, nullptr);
    }
  }

  // ---- final pseudo-norm in place on d_out ----
  norm_k<false><<<dim3(M_), thr, 0, stream>>>(o1, o1, nullptr);
}

// Round 9
// 556.305 us; speedup vs baseline: 7.0993x; 1.1025x over previous
//
#include <hip/hip_runtime.h>
#include <hip/hip_bf16.h>
#include <math.h>

// Encoder block. B=8, T=1024, D=1024, H=16, dk=dv=64, FF=4096.
// softmax in reference is over the QUERY axis (axis=2 of (B,H,Tq,Ts)).
// Round 9: GEMM gets (1) XCD-aware bijective block swizzle (T1),
// (2) LDS staging swizzle (slot ^ row&3) cutting read conflicts 8->4 way,
// (3) FF unchunked: hc = full 64MB hidden, FF1 N=4096 / FF2 K=4096 single
// launches (removes read-modify-write pass). Attention unchanged from r8.
//
// Workspace (~105 MB):
//  [0,16M)  qb16 -> o1b16 after attention
//  [16,32M) kb16 --\
//  [32,48M) Vt      \__ hc (64 MB FF hidden) after attention/Wo
//  [48,64M) xb16    /
//  [64,80M) part16-/   (xb dead after QKV; part16 dead after Wo)
//  [80,86M) Wqkv (3072 x 1024 Bt)  [86,88M) Wot
//  [88,96M) W1b  [96,104M) W2b   [104M..) Lrcp (1/l, fp32, B*H*T)

#define B_ 8
#define T_ 1024
#define D_ 1024
#define H_ 16
#define DK_ 64
#define FF_ 4096
#define M_ (B_ * T_) // 8192

typedef unsigned short u16;
typedef __attribute__((ext_vector_type(8))) short bf16x8;
typedef __attribute__((ext_vector_type(4))) float f32x4;

#define QSZ 8388608ull // 8192*1024 elements (16 MB bf16)

__device__ __forceinline__ float b2f(u16 u) {
  union { unsigned int i; float f; } x;
  x.i = ((unsigned int)u) << 16;
  return x.f;
}
__device__ __forceinline__ u16 f2b(float f) {
  __hip_bfloat16 h = __float2bfloat16(f); // RNE, single HW op on gfx950
  return *(u16*)&h;
}
__device__ __forceinline__ float fexp2(float x) {
#if __has_builtin(__builtin_amdgcn_exp2f)
  return __builtin_amdgcn_exp2f(x);
#else
  return exp2f(x);
#endif
}
#define C_QK 0.1803368801111244f // 0.125 * log2(e)

typedef __attribute__((address_space(1))) const void gas_void;
typedef __attribute__((address_space(3))) void las_void;
__device__ __forceinline__ void gload16(const void* g, void* l) {
  __builtin_amdgcn_global_load_lds((gas_void*)g, (las_void*)l, 16, 0, 0);
}

// ---------------------------------------------------------------------------
// bf16 MFMA GEMM, 2-phase double-buffered, XCD-swizzled 1D grid.
// C[M,N] = A[M,K] @ Bt[N,K]^T. 128x128 tile, BK=32, 4 waves.
// LDS staging: slot ^= (row&3) swizzle (write via pre-swizzled global col,
// read via matching XOR) -> 4-way max conflict on ds_read_b128.
// EPI: 1: C=acc+res   2: Cb=bf16(relu(acc+bias))   3: C=acc+bias+res
//      6: fused-QKV split (Cb base = qb16; +QSZ k; +2QSZ Vt)
// ---------------------------------------------------------------------------
template <int EPI>
__global__ __launch_bounds__(256) void gemm16_k(
    const u16* __restrict__ A, const u16* __restrict__ Bt,
    int M, int N, int K, int lda, int ldb, int nbx,
    float* __restrict__ C, int ldc, u16* __restrict__ Cb,
    const float* __restrict__ res, const float* __restrict__ bias) {
  __shared__ __align__(16) u16 As[2][128 * 32]; // 2 x 8 KB
  __shared__ __align__(16) u16 Bs[2][128 * 32];

  const int tid = threadIdx.x;
  const int lane = tid & 63, wv = tid >> 6;

  // XCD-aware bijective swizzle: gridDim.x % 8 == 0 by construction.
  const int nwg = (int)gridDim.x;
  const int sw = (blockIdx.x & 7) * (nwg >> 3) + (blockIdx.x >> 3);
  const int m0 = (sw / nbx) * 128, n0 = (sw % nbx) * 128;

  const int wr = (wv >> 1) * 64, wc = (wv & 1) * 64;

  f32x4 acc[4][4];
#pragma unroll
  for (int i = 0; i < 4; ++i)
#pragma unroll
    for (int j = 0; j < 4; ++j) acc[i][j] = (f32x4){0.f, 0.f, 0.f, 0.f};

  // staging: lane covers row wv*16 + (lane>>2) (+64 on 2nd issue),
  // LDS slot lane&3; global col pre-swizzled so LDS slot s of row r holds
  // global cols ((s ^ (r&3))*8 .. +8).
  const int srow = wv * 16 + (lane >> 2);
  const int scol = ((lane & 3) ^ ((lane >> 2) & 3)) * 8;
  const int fr = lane & 15, fj = lane >> 4; // frag row lane, k-slot

  const u16* gA0 = &A[(size_t)(m0 + srow) * lda + scol];
  const u16* gA1 = &A[(size_t)(m0 + srow + 64) * lda + scol];
  const u16* gB0 = &Bt[(size_t)(n0 + srow) * ldb + scol];
  const u16* gB1 = &Bt[(size_t)(n0 + srow + 64) * ldb + scol];

  gload16(gA0, &As[0][wv * 512]);
  gload16(gA1, &As[0][2048 + wv * 512]);
  gload16(gB0, &Bs[0][wv * 512]);
  gload16(gB1, &Bs[0][2048 + wv * 512]);
  __syncthreads();

  int cur = 0;
  for (int k0 = 0; k0 < K; k0 += 32) {
    if (k0 + 32 < K) {
      int nx = cur ^ 1, ko = k0 + 32;
      gload16(gA0 + ko, &As[nx][wv * 512]);
      gload16(gA1 + ko, &As[nx][2048 + wv * 512]);
      gload16(gB0 + ko, &Bs[nx][wv * 512]);
      gload16(gB1 + ko, &Bs[nx][2048 + wv * 512]);
    }
    bf16x8 af[4], bfr[4];
#pragma unroll
    for (int mi = 0; mi < 4; ++mi) {
      int row = wr + mi * 16 + fr;
      af[mi] = *(const bf16x8*)&As[cur][row * 32 + ((fj ^ (fr & 3)) * 8)];
    }
#pragma unroll
    for (int ni = 0; ni < 4; ++ni) {
      int row = wc + ni * 16 + fr;
      bfr[ni] = *(const bf16x8*)&Bs[cur][row * 32 + ((fj ^ (fr & 3)) * 8)];
    }
#pragma unroll
    for (int mi = 0; mi < 4; ++mi)
#pragma unroll
      for (int ni = 0; ni < 4; ++ni)
        acc[mi][ni] = __builtin_amdgcn_mfma_f32_16x16x32_bf16(
            af[mi], bfr[ni], acc[mi][ni], 0, 0, 0);
    __syncthreads();
    cur ^= 1;
  }

  const int fq = (lane >> 4) * 4;
#pragma unroll
  for (int mi = 0; mi < 4; ++mi) {
#pragma unroll
    for (int ni = 0; ni < 4; ++ni) {
      const int row = m0 + wr + mi * 16 + fq;
      const int col = n0 + wc + ni * 16 + fr;
      f32x4 v = acc[mi][ni];
      if (EPI == 6) {
        const int seg = col >> 10, cl = col & 1023; // wave-uniform seg
        if (seg < 2) { // Q or K, row-major (b,t,h*64+k)
          u16* dst = Cb + (size_t)seg * QSZ;
#pragma unroll
          for (int r = 0; r < 4; ++r)
            dst[(size_t)(row + r) * 1024 + cl] = f2b(v[r]);
        } else { // V, per-head transposed: Vt[((b*16+h)*64+v)*T + t]
          ushort4 w;
          w.x = f2b(v[0]); w.y = f2b(v[1]); w.z = f2b(v[2]); w.w = f2b(v[3]);
          size_t vidx = 2 * QSZ +
                        (((size_t)(row >> 10) * 16 + (cl >> 6)) * 64 +
                         (cl & 63)) * (size_t)T_ + (row & 1023);
          *(ushort4*)&Cb[vidx] = w;
        }
      } else {
#pragma unroll
        for (int r = 0; r < 4; ++r) {
          float val = v[r];
          size_t idx = (size_t)(row + r) * ldc + col;
          if (EPI == 1) {
            C[idx] = val + res[idx];
          } else if (EPI == 2) {
            Cb[idx] = f2b(fmaxf(val + bias[col], 0.f));
          } else if (EPI == 3) {
            C[idx] = val + bias[col] + res[idx];
          }
        }
      }
    }
  }
}

// ---------------------------------------------------------------------------
// fp32 -> bf16 elementwise convert
// ---------------------------------------------------------------------------
__global__ __launch_bounds__(256) void cvt_k(const float* __restrict__ in,
                                             u16* __restrict__ out, int n4) {
  int i = blockIdx.x * 256 + threadIdx.x;
  if (i >= n4) return;
  float4 v = *(const float4*)&in[(size_t)i * 4];
  ushort4 o;
  o.x = f2b(v.x); o.y = f2b(v.y); o.z = f2b(v.z); o.w = f2b(v.w);
  *(ushort4*)&out[(size_t)i * 4] = o;
}

// ---------------------------------------------------------------------------
// transpose-convert: src (R x C) fp32 -> dst (C x R) bf16, batched over z.
// ---------------------------------------------------------------------------
__global__ __launch_bounds__(256) void tconv_k(const float* __restrict__ src,
                                               u16* __restrict__ dst, int R,
                                               int C) {
  __shared__ __align__(16) float t[32][33];
  const size_t bo = (size_t)blockIdx.z * R * C;
  const int r0 = blockIdx.y * 32, c0 = blockIdx.x * 32;
  const int tid = threadIdx.x;
  const int row = tid >> 3, c4 = (tid & 7) * 4;
  float4 v = *(const float4*)&src[bo + (size_t)(r0 + row) * C + c0 + c4];
  t[row][c4 + 0] = v.x; t[row][c4 + 1] = v.y;
  t[row][c4 + 2] = v.z; t[row][c4 + 3] = v.w;
  __syncthreads();
  ushort4 o;
  o.x = f2b(t[c4 + 0][row]); o.y = f2b(t[c4 + 1][row]);
  o.z = f2b(t[c4 + 2][row]); o.w = f2b(t[c4 + 3][row]);
  *(ushort4*)&dst[bo + (size_t)(c0 + row) * R + r0 + c4] = o;
}

// ---------------------------------------------------------------------------
// Attention pass 1 (MFMA): Lrcp[b,h,s] = 1 / sum_q exp(S[q,s]/8)
// ---------------------------------------------------------------------------
__global__ __launch_bounds__(256) void attn_lsum_k(
    const u16* __restrict__ q, const u16* __restrict__ k,
    float* __restrict__ Lrcp) {
  __shared__ __align__(16) u16 Qs[128 * 64]; // 16 KB, swizzled
  __shared__ float Lsh[2][128];
  const int tid = threadIdx.x, lane = tid & 63, wv = tid >> 6;
  const int s0 = blockIdx.x * 128, h = blockIdx.y, b = blockIdx.z;
  const int bh = b * H_ + h;
  const u16* qbase = q + (size_t)b * T_ * D_ + h * DK_;
  const u16* kbase = k + (size_t)b * T_ * D_ + h * DK_;

  const int wr = (wv >> 1) * 64, wc = (wv & 1) * 64;
  const int fr = lane & 15, fs8 = (lane >> 4) * 8, fq = (lane >> 4) * 4;

  bf16x8 kf[4][2];
#pragma unroll
  for (int mi = 0; mi < 4; ++mi)
#pragma unroll
    for (int ks = 0; ks < 2; ++ks)
      kf[mi][ks] = *(const bf16x8*)&kbase[(size_t)(s0 + wr + mi * 16 + fr) * D_ +
                                          ks * 32 + fs8];

  float lrun[4][4];
#pragma unroll
  for (int mi = 0; mi < 4; ++mi)
#pragma unroll
    for (int r = 0; r < 4; ++r) lrun[mi][r] = 0.f;

  const int srow = wv * 8 + (lane >> 3);
  const int sscol = ((lane & 7) ^ ((lane >> 3) & 7)) * 8;

  for (int q0 = 0; q0 < T_; q0 += 128) {
    __syncthreads();
#pragma unroll
    for (int it = 0; it < 4; ++it)
      gload16(&qbase[(size_t)(q0 + it * 32 + srow) * D_ + sscol],
              &Qs[(it * 32 + wv * 8) * 64]);
    __syncthreads();

    f32x4 acc[4][4];
#pragma unroll
    for (int mi = 0; mi < 4; ++mi)
#pragma unroll
      for (int ni = 0; ni < 4; ++ni) acc[mi][ni] = (f32x4){0.f, 0.f, 0.f, 0.f};

#pragma unroll
    for (int ks = 0; ks < 2; ++ks) {
      bf16x8 qf[4];
#pragma unroll
      for (int ni = 0; ni < 4; ++ni) {
        int qr = wc + ni * 16 + fr;
        int slot = (ks * 4 + (lane >> 4)) ^ (qr & 7);
        qf[ni] = *(const bf16x8*)&Qs[qr * 64 + slot * 8];
      }
#pragma unroll
      for (int mi = 0; mi < 4; ++mi)
#pragma unroll
        for (int ni = 0; ni < 4; ++ni)
          acc[mi][ni] = __builtin_amdgcn_mfma_f32_16x16x32_bf16(
              kf[mi][ks], qf[ni], acc[mi][ni], 0, 0, 0);
    }
#pragma unroll
    for (int mi = 0; mi < 4; ++mi)
#pragma unroll
      for (int r = 0; r < 4; ++r) {
        float e = 0.f;
#pragma unroll
        for (int ni = 0; ni < 4; ++ni) e += fexp2(acc[mi][ni][r] * C_QK);
        lrun[mi][r] += e;
      }
  }

#pragma unroll
  for (int mi = 0; mi < 4; ++mi)
#pragma unroll
    for (int r = 0; r < 4; ++r) {
      float s = lrun[mi][r];
      s += __shfl_xor(s, 1, 64); s += __shfl_xor(s, 2, 64);
      s += __shfl_xor(s, 4, 64); s += __shfl_xor(s, 8, 64);
      if (fr == 0) Lsh[wv & 1][wr + mi * 16 + fq + r] = s;
    }
  __syncthreads();
  if (tid < 128)
    Lrcp[(size_t)bh * T_ + s0 + tid] = 1.f / (Lsh[0][tid] + Lsh[1][tid]);
}

// ---------------------------------------------------------------------------
// V pre-scale: Vt[(bh*64+v)*1024 + s] *= Lrcp[bh*1024 + s]  (8 u16/thread)
// ---------------------------------------------------------------------------
__global__ __launch_bounds__(256) void vscale_k(u16* __restrict__ vt,
                                                const float* __restrict__ Lrcp) {
  int i8 = blockIdx.x * 256 + threadIdx.x;
  size_t base = (size_t)i8 * 8;
  int bh = (int)(base >> 16);      // 64 v-rows * 1024 s per bh
  int s = (int)(base & 1023);
  float4 r0 = *(const float4*)&Lrcp[(size_t)bh * 1024 + s];
  float4 r1 = *(const float4*)&Lrcp[(size_t)bh * 1024 + s + 4];
  ushort4 a = *(const ushort4*)&vt[base];
  ushort4 c = *(const ushort4*)&vt[base + 4];
  ushort4 oa, oc;
  oa.x = f2b(b2f(a.x) * r0.x); oa.y = f2b(b2f(a.y) * r0.y);
  oa.z = f2b(b2f(a.z) * r0.z); oa.w = f2b(b2f(a.w) * r0.w);
  oc.x = f2b(b2f(c.x) * r1.x); oc.y = f2b(b2f(c.y) * r1.y);
  oc.z = f2b(b2f(c.z) * r1.z); oc.w = f2b(b2f(c.w) * r1.w);
  *(ushort4*)&vt[base] = oa;
  *(ushort4*)&vt[base + 4] = oc;
}

// ---------------------------------------------------------------------------
// Attention pass 2 (MFMA): part[q,v] = sum_s exp2(S[q,s]*C_QK) * V'[s,v]
// ---------------------------------------------------------------------------
__global__ __launch_bounds__(256) void attn_pv_k(
    const u16* __restrict__ q, const u16* __restrict__ k,
    const u16* __restrict__ vt, u16* __restrict__ part) {
  __shared__ __align__(16) u16 Ks[128 * 64];  // 16 KB swizzled
  __shared__ __align__(16) u16 Vs[64 * 128];  // 16 KB swizzled (v-major)
  __shared__ __align__(16) u16 Ps[128 * 128]; // 32 KB [q][s], ^(q&15)<<4
  const int tid = threadIdx.x, lane = tid & 63, wv = tid >> 6;
  const int q0 = blockIdx.x * 128, h = blockIdx.y, b = blockIdx.z;
  const int bh = b * H_ + h;
  const u16* qbase = q + (size_t)b * T_ * D_ + h * DK_;
  const u16* kbase = k + (size_t)b * T_ * D_ + h * DK_;
  const u16* vtb = vt + (size_t)bh * DK_ * T_;

  const int wr = (wv >> 1) * 64, wc = (wv & 1) * 64; // S^T quadrant: s, q
  const int fr = lane & 15, fs8 = (lane >> 4) * 8, fq = (lane >> 4) * 4;

  bf16x8 qf[4][2];
#pragma unroll
  for (int ni = 0; ni < 4; ++ni)
#pragma unroll
    for (int ks = 0; ks < 2; ++ks)
      qf[ni][ks] = *(const bf16x8*)&qbase[(size_t)(q0 + wc + ni * 16 + fr) * D_ +
                                          ks * 32 + fs8];

  f32x4 acc2[2][4];
#pragma unroll
  for (int i = 0; i < 2; ++i)
#pragma unroll
    for (int j = 0; j < 4; ++j) acc2[i][j] = (f32x4){0.f, 0.f, 0.f, 0.f};

  const int ksrow = wv * 8 + (lane >> 3);
  const int kscol = ((lane & 7) ^ ((lane >> 3) & 7)) * 8;

  for (int s0 = 0; s0 < T_; s0 += 128) {
    __syncthreads();
#pragma unroll
    for (int it = 0; it < 4; ++it)
      gload16(&kbase[(size_t)(s0 + it * 32 + ksrow) * D_ + kscol],
              &Ks[(it * 32 + wv * 8) * 64]);
#pragma unroll
    for (int it = 0; it < 4; ++it) {
      int v = it * 16 + wv * 4 + (lane >> 4);
      int sslot = (lane & 15) ^ (v & 7);
      gload16(&vtb[(size_t)v * T_ + s0 + sslot * 8],
              &Vs[(it * 16 + wv * 4) * 128]);
    }
    __syncthreads();

    f32x4 st[4][4];
#pragma unroll
    for (int mi = 0; mi < 4; ++mi)
#pragma unroll
      for (int ni = 0; ni < 4; ++ni) st[mi][ni] = (f32x4){0.f, 0.f, 0.f, 0.f};
#pragma unroll
    for (int ks = 0; ks < 2; ++ks) {
      bf16x8 kfa[4];
#pragma unroll
      for (int mi = 0; mi < 4; ++mi) {
        int sr = wr + mi * 16 + fr;
        int slot = (ks * 4 + (lane >> 4)) ^ (sr & 7);
        kfa[mi] = *(const bf16x8*)&Ks[sr * 64 + slot * 8];
      }
#pragma unroll
      for (int mi = 0; mi < 4; ++mi)
#pragma unroll
        for (int ni = 0; ni < 4; ++ni)
          st[mi][ni] = __builtin_amdgcn_mfma_f32_16x16x32_bf16(
              kfa[mi], qf[ni][ks], st[mi][ni], 0, 0, 0);
    }

    // P = exp2(S*C_QK) -> Ps[q][s], packed 8B (4 consecutive s per lane)
#pragma unroll
    for (int ni = 0; ni < 4; ++ni) {
      int qcol = wc + ni * 16 + fr;
#pragma unroll
      for (int mi = 0; mi < 4; ++mi) {
        int sb = wr + mi * 16 + fq; // 4 consecutive s, 8B aligned
        u16 e0 = f2b(fexp2(st[mi][ni][0] * C_QK));
        u16 e1 = f2b(fexp2(st[mi][ni][1] * C_QK));
        u16 e2 = f2b(fexp2(st[mi][ni][2] * C_QK));
        u16 e3 = f2b(fexp2(st[mi][ni][3] * C_QK));
        uint2 w;
        w.x = (unsigned int)e0 | ((unsigned int)e1 << 16);
        w.y = (unsigned int)e2 | ((unsigned int)e3 << 16);
        int byte = qcol * 256 + ((sb * 2) ^ ((qcol & 15) << 4));
        *(uint2*)((char*)Ps + byte) = w;
      }
    }
    __syncthreads();

#pragma unroll
    for (int ks2 = 0; ks2 < 4; ++ks2) {
      bf16x8 pa[2], vb2[4];
#pragma unroll
      for (int mi2 = 0; mi2 < 2; ++mi2) {
        int qr = wv * 32 + mi2 * 16 + fr;
        int byte = qr * 256 + (((ks2 * 32 + (lane >> 4) * 8) * 2) ^ ((qr & 15) << 4));
        pa[mi2] = *(const bf16x8*)((const char*)Ps + byte);
      }
#pragma unroll
      for (int ni2 = 0; ni2 < 4; ++ni2) {
        int v = ni2 * 16 + fr;
        int slot = (ks2 * 4 + (lane >> 4)) ^ (v & 7);
        vb2[ni2] = *(const bf16x8*)&Vs[v * 128 + slot * 8];
      }
#pragma unroll
      for (int mi2 = 0; mi2 < 2; ++mi2)
#pragma unroll
        for (int ni2 = 0; ni2 < 4; ++ni2)
          acc2[mi2][ni2] = __builtin_amdgcn_mfma_f32_16x16x32_bf16(
              pa[mi2], vb2[ni2], acc2[mi2][ni2], 0, 0, 0);
    }
  }

#pragma unroll
  for (int mi2 = 0; mi2 < 2; ++mi2)
#pragma unroll
    for (int ni2 = 0; ni2 < 4; ++ni2)
#pragma unroll
      for (int r = 0; r < 4; ++r) {
        int qrow = q0 + wv * 32 + mi2 * 16 + fq + r;
        int v = ni2 * 16 + fr;
        part[(size_t)(b * T_ + qrow) * D_ + h * DK_ + v] =
            f2b(acc2[mi2][ni2][r]);
      }
}

// ---------------------------------------------------------------------------
// Pseudo-norm: y - mean(y) - std(y, ddof=1) per row of 1024. In-place safe.
// ---------------------------------------------------------------------------
template <bool WB>
__global__ __launch_bounds__(256) void norm_k(const float* __restrict__ in,
                                              float* __restrict__ out,
                                              u16* __restrict__ ob) {
  __shared__ float red[8];
  const int row = blockIdx.x, tid = threadIdx.x;
  float4 vv = *(const float4*)&in[(size_t)row * D_ + tid * 4];
  float s = vv.x + vv.y + vv.z + vv.w;
  for (int off = 1; off < 64; off <<= 1) s += __shfl_xor(s, off, 64);
  if ((tid & 63) == 0) red[tid >> 6] = s;
  __syncthreads();
  float mean = (red[0] + red[1] + red[2] + red[3]) * (1.f / 1024.f);
  float dx = vv.x - mean, dy = vv.y - mean, dz = vv.z - mean, dw = vv.w - mean;
  float s2 = dx * dx + dy * dy + dz * dz + dw * dw;
  __syncthreads();
  for (int off = 1; off < 64; off <<= 1) s2 += __shfl_xor(s2, off, 64);
  if ((tid & 63) == 0) red[4 + (tid >> 6)] = s2;
  __syncthreads();
  float var = (red[4] + red[5] + red[6] + red[7]) * (1.f / 1023.f);
  float sd = sqrtf(var);
  float4 o = {dx - sd, dy - sd, dz - sd, dw - sd};
  *(float4*)&out[(size_t)row * D_ + tid * 4] = o;
  if (WB) {
    ushort4 q;
    q.x = f2b(o.x); q.y = f2b(o.y); q.z = f2b(o.z); q.w = f2b(o.w);
    *(ushort4*)&ob[(size_t)row * D_ + tid * 4] = q;
  }
}

// ---------------------------------------------------------------------------
extern "C" void kernel_launch(void* const* d_in, const int* in_sizes, int n_in,
                              void* d_out, int out_size, void* d_ws,
                              size_t ws_size, hipStream_t stream) {
  const float* x  = (const float*)d_in[0];
  const float* Wq = (const float*)d_in[1];
  const float* Wk = (const float*)d_in[2];
  const float* Wv = (const float*)d_in[3];
  const float* Wo = (const float*)d_in[4];
  const float* W1 = (const float*)d_in[5];
  const float* b1 = (const float*)d_in[6];
  const float* W2 = (const float*)d_in[7];
  const float* b2 = (const float*)d_in[8];

  char* w = (char*)d_ws;
  u16* qb16   = (u16*)(w + (0ull << 20));  // +QSZ: kb16, +2*QSZ: Vt
  u16* kb16   = (u16*)(w + (16ull << 20));
  u16* Vt     = (u16*)(w + (32ull << 20));
  u16* xb     = (u16*)(w + (48ull << 20));
  u16* part16 = (u16*)(w + (64ull << 20));
  u16* Wqkv   = (u16*)(w + (80ull << 20)); // 3072 x 1024 Bt (Wq|Wk|Wv)
  u16* Wot    = (u16*)(w + (86ull << 20));
  u16* W1b    = (u16*)(w + (88ull << 20));
  u16* W2b    = (u16*)(w + (96ull << 20));
  float* Lrcp = (float*)(w + (104ull << 20));
  u16* o1b = qb16;            // after attention
  u16* hc  = kb16;            // 64 MB [16,80M) after attention + Wo GEMM
  float* o1 = (float*)d_out;

  dim3 thr(256);

  // ---- convert weights/activations to bf16 (Bt layout = N x K) ----
  int n4x = (M_ * D_) / 4;
  cvt_k<<<dim3((n4x + 255) / 256), thr, 0, stream>>>(x, xb, n4x);
  tconv_k<<<dim3(2, 32, 16), thr, 0, stream>>>(Wq, Wqkv, 1024, 64);
  tconv_k<<<dim3(2, 32, 16), thr, 0, stream>>>(Wk, Wqkv + 1048576, 1024, 64);
  tconv_k<<<dim3(2, 32, 16), thr, 0, stream>>>(Wv, Wqkv + 2097152, 1024, 64);
  tconv_k<<<dim3(32, 32, 1), thr, 0, stream>>>(Wo, Wot, 1024, 1024);
  int n4w = (FF_ * D_) / 4;
  cvt_k<<<dim3((n4w + 255) / 256), thr, 0, stream>>>(W1, W1b, n4w);
  cvt_k<<<dim3((n4w + 255) / 256), thr, 0, stream>>>(W2, W2b, n4w);

  // ---- fused QKV projection (N=3072; epilogue splits Q/K row-major, V^T) --
  gemm16_k<6><<<dim3((3072 / 128) * (M_ / 128)), thr, 0, stream>>>(
      xb, Wqkv, M_, 3072, D_, D_, D_, 3072 / 128, nullptr, D_, qb16,
      nullptr, nullptr);

  // ---- attention (query-axis softmax, no-max two-pass, MFMA) ----
  dim3 ga(T_ / 128, H_, B_);
  attn_lsum_k<<<ga, thr, 0, stream>>>(qb16, kb16, Lrcp);
  vscale_k<<<dim3((int)(QSZ / 8 / 256)), thr, 0, stream>>>(Vt, Lrcp);
  attn_pv_k<<<ga, thr, 0, stream>>>(qb16, kb16, Vt, part16);

  // ---- out1 = part @ Wo + x -> d_out (fp32); pseudo-norm + bf16 copy ----
  gemm16_k<1><<<dim3((D_ / 128) * (M_ / 128)), thr, 0, stream>>>(
      part16, Wot, M_, D_, D_, D_, D_, D_ / 128, o1, D_, nullptr, x, nullptr);
  norm_k<true><<<dim3(M_), thr, 0, stream>>>(o1, o1, o1b);

  // ---- FF, unchunked: hc = relu(o1b @ W1^T + b1); out = hc @ W2^T + b2 + o1
  gemm16_k<2><<<dim3((FF_ / 128) * (M_ / 128)), thr, 0, stream>>>(
      o1b, W1b, M_, FF_, D_, D_, D_, FF_ / 128, nullptr, FF_, hc,
      nullptr, b1);
  gemm16_k<3><<<dim3((D_ / 128) * (M_ / 128)), thr, 0, stream>>>(
      hc, W2b, M_, D_, FF_, FF_, FF_, D_ / 128, o1, D_, nullptr, o1, b2);

  // ---- final pseudo-norm in place on d_out ----
  norm_k<false><<<dim3(M_), thr, 0, stream>>>(o1, o1, nullptr);
}

// Round 11
// 553.248 us; speedup vs baseline: 7.1386x; 1.0055x over previous
//
#include <hip/hip_runtime.h>
#include <hip/hip_bf16.h>
#include <math.h>

// Encoder block. B=8, T=1024, D=1024, H=16, dk=dv=64, FF=4096.
// softmax in reference is over the QUERY axis (axis=2 of (B,H,Tq,Ts)).
// Round 11 == Round 10 resubmit (GPU acquisition timeout; never executed).
// GEMM pipeline: 3-buffer depth-2 counted-vmcnt schedule (T4):
// per iter: issue gloads(t+2) -> s_waitcnt vmcnt(8) -> s_barrier -> compute(t)
// -> s_barrier. Raw barriers (no compiler vmcnt(0) drain); loads stay in
// flight across 2 compute phases. Attention unchanged from r9.
//
// Workspace (~105 MB): same map as r9.

#define B_ 8
#define T_ 1024
#define D_ 1024
#define H_ 16
#define DK_ 64
#define FF_ 4096
#define M_ (B_ * T_) // 8192

typedef unsigned short u16;
typedef __attribute__((ext_vector_type(8))) short bf16x8;
typedef __attribute__((ext_vector_type(4))) float f32x4;

#define QSZ 8388608ull // 8192*1024 elements (16 MB bf16)

__device__ __forceinline__ float b2f(u16 u) {
  union { unsigned int i; float f; } x;
  x.i = ((unsigned int)u) << 16;
  return x.f;
}
__device__ __forceinline__ u16 f2b(float f) {
  __hip_bfloat16 h = __float2bfloat16(f); // RNE, single HW op on gfx950
  return *(u16*)&h;
}
__device__ __forceinline__ float fexp2(float x) {
#if __has_builtin(__builtin_amdgcn_exp2f)
  return __builtin_amdgcn_exp2f(x);
#else
  return exp2f(x);
#endif
}
#define C_QK 0.1803368801111244f // 0.125 * log2(e)

typedef __attribute__((address_space(1))) const void gas_void;
typedef __attribute__((address_space(3))) void las_void;
__device__ __forceinline__ void gload16(const void* g, void* l) {
  __builtin_amdgcn_global_load_lds((gas_void*)g, (las_void*)l, 16, 0, 0);
}

// ---------------------------------------------------------------------------
// bf16 MFMA GEMM, 3-buffer depth-2 counted-vmcnt pipeline, XCD-swizzled grid.
// C[M,N] = A[M,K] @ Bt[N,K]^T. 128x128 tile, BK=32, 4 waves, 48KB LDS.
// Schedule per iter t: STAGE(t+2, buf[(t+2)%3]) ; vmcnt(8) ; s_barrier ;
//   ds_read+MFMA from buf[t%3] ; s_barrier.
// vmcnt(8) = the 8 loads of tiles t+1,t+2 may remain in flight; tile t's 4
// loads (issued 2 iters ago) are guaranteed complete. WAR: buffer read at t
// is re-written by the stage issued at t+1, after the trailing barrier.
// EPI: 1: C=acc+res   2: Cb=bf16(relu(acc+bias))   3: C=acc+bias+res
//      6: fused-QKV split (Cb base = qb16; +QSZ k; +2QSZ Vt)
// ---------------------------------------------------------------------------
template <int EPI>
__global__ __launch_bounds__(256) void gemm16_k(
    const u16* __restrict__ A, const u16* __restrict__ Bt,
    int M, int N, int K, int lda, int ldb, int nbx,
    float* __restrict__ C, int ldc, u16* __restrict__ Cb,
    const float* __restrict__ res, const float* __restrict__ bias) {
  __shared__ __align__(16) u16 As[3][128 * 32]; // 3 x 8 KB
  __shared__ __align__(16) u16 Bs[3][128 * 32];

  const int tid = threadIdx.x;
  const int lane = tid & 63, wv = tid >> 6;

  // XCD-aware bijective swizzle: gridDim.x % 8 == 0 by construction.
  const int nwg = (int)gridDim.x;
  const int sw = (blockIdx.x & 7) * (nwg >> 3) + (blockIdx.x >> 3);
  const int m0 = (sw / nbx) * 128, n0 = (sw % nbx) * 128;

  const int wr = (wv >> 1) * 64, wc = (wv & 1) * 64;

  f32x4 acc[4][4];
#pragma unroll
  for (int i = 0; i < 4; ++i)
#pragma unroll
    for (int j = 0; j < 4; ++j) acc[i][j] = (f32x4){0.f, 0.f, 0.f, 0.f};

  // staging: lane covers row wv*16 + (lane>>2) (+64 on 2nd issue), LDS slot
  // lane&3; global col pre-swizzled: slot s of row r holds cols (s^(r&3))*8.
  const int srow = wv * 16 + (lane >> 2);
  const int scol = ((lane & 3) ^ ((lane >> 2) & 3)) * 8;
  const int fr = lane & 15, fj = lane >> 4; // frag row lane, k-slot

  const u16* gA0 = &A[(size_t)(m0 + srow) * lda + scol];
  const u16* gA1 = &A[(size_t)(m0 + srow + 64) * lda + scol];
  const u16* gB0 = &Bt[(size_t)(n0 + srow) * ldb + scol];
  const u16* gB1 = &Bt[(size_t)(n0 + srow + 64) * ldb + scol];

  const int nt = K >> 5;
#define STAGE(t, bf)                                    \
  do {                                                  \
    int ko_ = (t) * 32;                                 \
    gload16(gA0 + ko_, &As[bf][wv * 512]);              \
    gload16(gA1 + ko_, &As[bf][2048 + wv * 512]);       \
    gload16(gB0 + ko_, &Bs[bf][wv * 512]);              \
    gload16(gB1 + ko_, &Bs[bf][2048 + wv * 512]);       \
  } while (0)

  STAGE(0, 0);
  STAGE(1, 1);

  int bi = 0;
  for (int t = 0; t < nt; ++t) {
    int nx = bi + 2; if (nx >= 3) nx -= 3;
    if (t + 2 < nt) {
      STAGE(t + 2, nx);
      asm volatile("s_waitcnt vmcnt(8)" ::: "memory");
    } else if (t + 1 < nt) {
      asm volatile("s_waitcnt vmcnt(4)" ::: "memory");
    } else {
      asm volatile("s_waitcnt vmcnt(0)" ::: "memory");
    }
    __builtin_amdgcn_s_barrier();
    __builtin_amdgcn_sched_barrier(0);

    bf16x8 af[4], bfr[4];
#pragma unroll
    for (int mi = 0; mi < 4; ++mi) {
      int row = wr + mi * 16 + fr;
      af[mi] = *(const bf16x8*)&As[bi][row * 32 + ((fj ^ (fr & 3)) * 8)];
    }
#pragma unroll
    for (int ni = 0; ni < 4; ++ni) {
      int row = wc + ni * 16 + fr;
      bfr[ni] = *(const bf16x8*)&Bs[bi][row * 32 + ((fj ^ (fr & 3)) * 8)];
    }
#pragma unroll
    for (int mi = 0; mi < 4; ++mi)
#pragma unroll
      for (int ni = 0; ni < 4; ++ni)
        acc[mi][ni] = __builtin_amdgcn_mfma_f32_16x16x32_bf16(
            af[mi], bfr[ni], acc[mi][ni], 0, 0, 0);

    __builtin_amdgcn_sched_barrier(0);
    __builtin_amdgcn_s_barrier();
    bi = (bi + 1 == 3) ? 0 : bi + 1;
  }
#undef STAGE

  const int fq = (lane >> 4) * 4;
#pragma unroll
  for (int mi = 0; mi < 4; ++mi) {
#pragma unroll
    for (int ni = 0; ni < 4; ++ni) {
      const int row = m0 + wr + mi * 16 + fq;
      const int col = n0 + wc + ni * 16 + fr;
      f32x4 v = acc[mi][ni];
      if (EPI == 6) {
        const int seg = col >> 10, cl = col & 1023; // wave-uniform seg
        if (seg < 2) { // Q or K, row-major (b,t,h*64+k)
          u16* dst = Cb + (size_t)seg * QSZ;
#pragma unroll
          for (int r = 0; r < 4; ++r)
            dst[(size_t)(row + r) * 1024 + cl] = f2b(v[r]);
        } else { // V, per-head transposed: Vt[((b*16+h)*64+v)*T + t]
          ushort4 w;
          w.x = f2b(v[0]); w.y = f2b(v[1]); w.z = f2b(v[2]); w.w = f2b(v[3]);
          size_t vidx = 2 * QSZ +
                        (((size_t)(row >> 10) * 16 + (cl >> 6)) * 64 +
                         (cl & 63)) * (size_t)T_ + (row & 1023);
          *(ushort4*)&Cb[vidx] = w;
        }
      } else {
#pragma unroll
        for (int r = 0; r < 4; ++r) {
          float val = v[r];
          size_t idx = (size_t)(row + r) * ldc + col;
          if (EPI == 1) {
            C[idx] = val + res[idx];
          } else if (EPI == 2) {
            Cb[idx] = f2b(fmaxf(val + bias[col], 0.f));
          } else if (EPI == 3) {
            C[idx] = val + bias[col] + res[idx];
          }
        }
      }
    }
  }
}

// ---------------------------------------------------------------------------
// fp32 -> bf16 elementwise convert
// ---------------------------------------------------------------------------
__global__ __launch_bounds__(256) void cvt_k(const float* __restrict__ in,
                                             u16* __restrict__ out, int n4) {
  int i = blockIdx.x * 256 + threadIdx.x;
  if (i >= n4) return;
  float4 v = *(const float4*)&in[(size_t)i * 4];
  ushort4 o;
  o.x = f2b(v.x); o.y = f2b(v.y); o.z = f2b(v.z); o.w = f2b(v.w);
  *(ushort4*)&out[(size_t)i * 4] = o;
}

// ---------------------------------------------------------------------------
// transpose-convert: src (R x C) fp32 -> dst (C x R) bf16, batched over z.
// ---------------------------------------------------------------------------
__global__ __launch_bounds__(256) void tconv_k(const float* __restrict__ src,
                                               u16* __restrict__ dst, int R,
                                               int C) {
  __shared__ __align__(16) float t[32][33];
  const size_t bo = (size_t)blockIdx.z * R * C;
  const int r0 = blockIdx.y * 32, c0 = blockIdx.x * 32;
  const int tid = threadIdx.x;
  const int row = tid >> 3, c4 = (tid & 7) * 4;
  float4 v = *(const float4*)&src[bo + (size_t)(r0 + row) * C + c0 + c4];
  t[row][c4 + 0] = v.x; t[row][c4 + 1] = v.y;
  t[row][c4 + 2] = v.z; t[row][c4 + 3] = v.w;
  __syncthreads();
  ushort4 o;
  o.x = f2b(t[c4 + 0][row]); o.y = f2b(t[c4 + 1][row]);
  o.z = f2b(t[c4 + 2][row]); o.w = f2b(t[c4 + 3][row]);
  *(ushort4*)&dst[bo + (size_t)(c0 + row) * R + r0 + c4] = o;
}

// ---------------------------------------------------------------------------
// Attention pass 1 (MFMA): Lrcp[b,h,s] = 1 / sum_q exp(S[q,s]/8)
// ---------------------------------------------------------------------------
__global__ __launch_bounds__(256) void attn_lsum_k(
    const u16* __restrict__ q, const u16* __restrict__ k,
    float* __restrict__ Lrcp) {
  __shared__ __align__(16) u16 Qs[128 * 64]; // 16 KB, swizzled
  __shared__ float Lsh[2][128];
  const int tid = threadIdx.x, lane = tid & 63, wv = tid >> 6;
  const int s0 = blockIdx.x * 128, h = blockIdx.y, b = blockIdx.z;
  const int bh = b * H_ + h;
  const u16* qbase = q + (size_t)b * T_ * D_ + h * DK_;
  const u16* kbase = k + (size_t)b * T_ * D_ + h * DK_;

  const int wr = (wv >> 1) * 64, wc = (wv & 1) * 64;
  const int fr = lane & 15, fs8 = (lane >> 4) * 8, fq = (lane >> 4) * 4;

  bf16x8 kf[4][2];
#pragma unroll
  for (int mi = 0; mi < 4; ++mi)
#pragma unroll
    for (int ks = 0; ks < 2; ++ks)
      kf[mi][ks] = *(const bf16x8*)&kbase[(size_t)(s0 + wr + mi * 16 + fr) * D_ +
                                          ks * 32 + fs8];

  float lrun[4][4];
#pragma unroll
  for (int mi = 0; mi < 4; ++mi)
#pragma unroll
    for (int r = 0; r < 4; ++r) lrun[mi][r] = 0.f;

  const int srow = wv * 8 + (lane >> 3);
  const int sscol = ((lane & 7) ^ ((lane >> 3) & 7)) * 8;

  for (int q0 = 0; q0 < T_; q0 += 128) {
    __syncthreads();
#pragma unroll
    for (int it = 0; it < 4; ++it)
      gload16(&qbase[(size_t)(q0 + it * 32 + srow) * D_ + sscol],
              &Qs[(it * 32 + wv * 8) * 64]);
    __syncthreads();

    f32x4 acc[4][4];
#pragma unroll
    for (int mi = 0; mi < 4; ++mi)
#pragma unroll
      for (int ni = 0; ni < 4; ++ni) acc[mi][ni] = (f32x4){0.f, 0.f, 0.f, 0.f};

#pragma unroll
    for (int ks = 0; ks < 2; ++ks) {
      bf16x8 qf[4];
#pragma unroll
      for (int ni = 0; ni < 4; ++ni) {
        int qr = wc + ni * 16 + fr;
        int slot = (ks * 4 + (lane >> 4)) ^ (qr & 7);
        qf[ni] = *(const bf16x8*)&Qs[qr * 64 + slot * 8];
      }
#pragma unroll
      for (int mi = 0; mi < 4; ++mi)
#pragma unroll
        for (int ni = 0; ni < 4; ++ni)
          acc[mi][ni] = __builtin_amdgcn_mfma_f32_16x16x32_bf16(
              kf[mi][ks], qf[ni], acc[mi][ni], 0, 0, 0);
    }
#pragma unroll
    for (int mi = 0; mi < 4; ++mi)
#pragma unroll
      for (int r = 0; r < 4; ++r) {
        float e = 0.f;
#pragma unroll
        for (int ni = 0; ni < 4; ++ni) e += fexp2(acc[mi][ni][r] * C_QK);
        lrun[mi][r] += e;
      }
  }

#pragma unroll
  for (int mi = 0; mi < 4; ++mi)
#pragma unroll
    for (int r = 0; r < 4; ++r) {
      float s = lrun[mi][r];
      s += __shfl_xor(s, 1, 64); s += __shfl_xor(s, 2, 64);
      s += __shfl_xor(s, 4, 64); s += __shfl_xor(s, 8, 64);
      if (fr == 0) Lsh[wv & 1][wr + mi * 16 + fq + r] = s;
    }
  __syncthreads();
  if (tid < 128)
    Lrcp[(size_t)bh * T_ + s0 + tid] = 1.f / (Lsh[0][tid] + Lsh[1][tid]);
}

// ---------------------------------------------------------------------------
// V pre-scale: Vt[(bh*64+v)*1024 + s] *= Lrcp[bh*1024 + s]  (8 u16/thread)
// ---------------------------------------------------------------------------
__global__ __launch_bounds__(256) void vscale_k(u16* __restrict__ vt,
                                                const float* __restrict__ Lrcp) {
  int i8 = blockIdx.x * 256 + threadIdx.x;
  size_t base = (size_t)i8 * 8;
  int bh = (int)(base >> 16);      // 64 v-rows * 1024 s per bh
  int s = (int)(base & 1023);
  float4 r0 = *(const float4*)&Lrcp[(size_t)bh * 1024 + s];
  float4 r1 = *(const float4*)&Lrcp[(size_t)bh * 1024 + s + 4];
  ushort4 a = *(const ushort4*)&vt[base];
  ushort4 c = *(const ushort4*)&vt[base + 4];
  ushort4 oa, oc;
  oa.x = f2b(b2f(a.x) * r0.x); oa.y = f2b(b2f(a.y) * r0.y);
  oa.z = f2b(b2f(a.z) * r0.z); oa.w = f2b(b2f(a.w) * r0.w);
  oc.x = f2b(b2f(c.x) * r1.x); oc.y = f2b(b2f(c.y) * r1.y);
  oc.z = f2b(b2f(c.z) * r1.z); oc.w = f2b(b2f(c.w) * r1.w);
  *(ushort4*)&vt[base] = oa;
  *(ushort4*)&vt[base + 4] = oc;
}

// ---------------------------------------------------------------------------
// Attention pass 2 (MFMA): part[q,v] = sum_s exp2(S[q,s]*C_QK) * V'[s,v]
// ---------------------------------------------------------------------------
__global__ __launch_bounds__(256) void attn_pv_k(
    const u16* __restrict__ q, const u16* __restrict__ k,
    const u16* __restrict__ vt, u16* __restrict__ part) {
  __shared__ __align__(16) u16 Ks[128 * 64];  // 16 KB swizzled
  __shared__ __align__(16) u16 Vs[64 * 128];  // 16 KB swizzled (v-major)
  __shared__ __align__(16) u16 Ps[128 * 128]; // 32 KB [q][s], ^(q&15)<<4
  const int tid = threadIdx.x, lane = tid & 63, wv = tid >> 6;
  const int q0 = blockIdx.x * 128, h = blockIdx.y, b = blockIdx.z;
  const int bh = b * H_ + h;
  const u16* qbase = q + (size_t)b * T_ * D_ + h * DK_;
  const u16* kbase = k + (size_t)b * T_ * D_ + h * DK_;
  const u16* vtb = vt + (size_t)bh * DK_ * T_;

  const int wr = (wv >> 1) * 64, wc = (wv & 1) * 64; // S^T quadrant: s, q
  const int fr = lane & 15, fs8 = (lane >> 4) * 8, fq = (lane >> 4) * 4;

  bf16x8 qf[4][2];
#pragma unroll
  for (int ni = 0; ni < 4; ++ni)
#pragma unroll
    for (int ks = 0; ks < 2; ++ks)
      qf[ni][ks] = *(const bf16x8*)&qbase[(size_t)(q0 + wc + ni * 16 + fr) * D_ +
                                          ks * 32 + fs8];

  f32x4 acc2[2][4];
#pragma unroll
  for (int i = 0; i < 2; ++i)
#pragma unroll
    for (int j = 0; j < 4; ++j) acc2[i][j] = (f32x4){0.f, 0.f, 0.f, 0.f};

  const int ksrow = wv * 8 + (lane >> 3);
  const int kscol = ((lane & 7) ^ ((lane >> 3) & 7)) * 8;

  for (int s0 = 0; s0 < T_; s0 += 128) {
    __syncthreads();
#pragma unroll
    for (int it = 0; it < 4; ++it)
      gload16(&kbase[(size_t)(s0 + it * 32 + ksrow) * D_ + kscol],
              &Ks[(it * 32 + wv * 8) * 64]);
#pragma unroll
    for (int it = 0; it < 4; ++it) {
      int v = it * 16 + wv * 4 + (lane >> 4);
      int sslot = (lane & 15) ^ (v & 7);
      gload16(&vtb[(size_t)v * T_ + s0 + sslot * 8],
              &Vs[(it * 16 + wv * 4) * 128]);
    }
    __syncthreads();

    f32x4 st[4][4];
#pragma unroll
    for (int mi = 0; mi < 4; ++mi)
#pragma unroll
      for (int ni = 0; ni < 4; ++ni) st[mi][ni] = (f32x4){0.f, 0.f, 0.f, 0.f};
#pragma unroll
    for (int ks = 0; ks < 2; ++ks) {
      bf16x8 kfa[4];
#pragma unroll
      for (int mi = 0; mi < 4; ++mi) {
        int sr = wr + mi * 16 + fr;
        int slot = (ks * 4 + (lane >> 4)) ^ (sr & 7);
        kfa[mi] = *(const bf16x8*)&Ks[sr * 64 + slot * 8];
      }
#pragma unroll
      for (int mi = 0; mi < 4; ++mi)
#pragma unroll
        for (int ni = 0; ni < 4; ++ni)
          st[mi][ni] = __builtin_amdgcn_mfma_f32_16x16x32_bf16(
              kfa[mi], qf[ni][ks], st[mi][ni], 0, 0, 0);
    }

    // P = exp2(S*C_QK) -> Ps[q][s], packed 8B (4 consecutive s per lane)
#pragma unroll
    for (int ni = 0; ni < 4; ++ni) {
      int qcol = wc + ni * 16 + fr;
#pragma unroll
      for (int mi = 0; mi < 4; ++mi) {
        int sb = wr + mi * 16 + fq; // 4 consecutive s, 8B aligned
        u16 e0 = f2b(fexp2(st[mi][ni][0] * C_QK));
        u16 e1 = f2b(fexp2(st[mi][ni][1] * C_QK));
        u16 e2 = f2b(fexp2(st[mi][ni][2] * C_QK));
        u16 e3 = f2b(fexp2(st[mi][ni][3] * C_QK));
        uint2 w;
        w.x = (unsigned int)e0 | ((unsigned int)e1 << 16);
        w.y = (unsigned int)e2 | ((unsigned int)e3 << 16);
        int byte = qcol * 256 + ((sb * 2) ^ ((qcol & 15) << 4));
        *(uint2*)((char*)Ps + byte) = w;
      }
    }
    __syncthreads();

#pragma unroll
    for (int ks2 = 0; ks2 < 4; ++ks2) {
      bf16x8 pa[2], vb2[4];
#pragma unroll
      for (int mi2 = 0; mi2 < 2; ++mi2) {
        int qr = wv * 32 + mi2 * 16 + fr;
        int byte = qr * 256 + (((ks2 * 32 + (lane >> 4) * 8) * 2) ^ ((qr & 15) << 4));
        pa[mi2] = *(const bf16x8*)((const char*)Ps + byte);
      }
#pragma unroll
      for (int ni2 = 0; ni2 < 4; ++ni2) {
        int v = ni2 * 16 + fr;
        int slot = (ks2 * 4 + (lane >> 4)) ^ (v & 7);
        vb2[ni2] = *(const bf16x8*)&Vs[v * 128 + slot * 8];
      }
#pragma unroll
      for (int mi2 = 0; mi2 < 2; ++mi2)
#pragma unroll
        for (int ni2 = 0; ni2 < 4; ++ni2)
          acc2[mi2][ni2] = __builtin_amdgcn_mfma_f32_16x16x32_bf16(
              pa[mi2], vb2[ni2], acc2[mi2][ni2], 0, 0, 0);
    }
  }

#pragma unroll
  for (int mi2 = 0; mi2 < 2; ++mi2)
#pragma unroll
    for (int ni2 = 0; ni2 < 4; ++ni2)
#pragma unroll
      for (int r = 0; r < 4; ++r) {
        int qrow = q0 + wv * 32 + mi2 * 16 + fq + r;
        int v = ni2 * 16 + fr;
        part[(size_t)(b * T_ + qrow) * D_ + h * DK_ + v] =
            f2b(acc2[mi2][ni2][r]);
      }
}

// ---------------------------------------------------------------------------
// Pseudo-norm: y - mean(y) - std(y, ddof=1) per row of 1024. In-place safe.
// ---------------------------------------------------------------------------
template <bool WB>
__global__ __launch_bounds__(256) void norm_k(const float* __restrict__ in,
                                              float* __restrict__ out,
                                              u16* __restrict__ ob) {
  __shared__ float red[8];
  const int row = blockIdx.x, tid = threadIdx.x;
  float4 vv = *(const float4*)&in[(size_t)row * D_ + tid * 4];
  float s = vv.x + vv.y + vv.z + vv.w;
  for (int off = 1; off < 64; off <<= 1) s += __shfl_xor(s, off, 64);
  if ((tid & 63) == 0) red[tid >> 6] = s;
  __syncthreads();
  float mean = (red[0] + red[1] + red[2] + red[3]) * (1.f / 1024.f);
  float dx = vv.x - mean, dy = vv.y - mean, dz = vv.z - mean, dw = vv.w - mean;
  float s2 = dx * dx + dy * dy + dz * dz + dw * dw;
  __syncthreads();
  for (int off = 1; off < 64; off <<= 1) s2 += __shfl_xor(s2, off, 64);
  if ((tid & 63) == 0) red[4 + (tid >> 6)] = s2;
  __syncthreads();
  float var = (red[4] + red[5] + red[6] + red[7]) * (1.f / 1023.f);
  float sd = sqrtf(var);
  float4 o = {dx - sd, dy - sd, dz - sd, dw - sd};
  *(float4*)&out[(size_t)row * D_ + tid * 4] = o;
  if (WB) {
    ushort4 q;
    q.x = f2b(o.x); q.y = f2b(o.y); q.z = f2b(o.z); q.w = f2b(o.w);
    *(ushort4*)&ob[(size_t)row * D_ + tid * 4] = q;
  }
}

// ---------------------------------------------------------------------------
extern "C" void kernel_launch(void* const* d_in, const int* in_sizes, int n_in,
                              void* d_out, int out_size, void* d_ws,
                              size_t ws_size, hipStream_t stream) {
  const float* x  = (const float*)d_in[0];
  const float* Wq = (const float*)d_in[1];
  const float* Wk = (const float*)d_in[2];
  const float* Wv = (const float*)d_in[3];
  const float* Wo = (const float*)d_in[4];
  const float* W1 = (const float*)d_in[5];
  const float* b1 = (const float*)d_in[6];
  const float* W2 = (const float*)d_in[7];
  const float* b2 = (const float*)d_in[8];

  char* w = (char*)d_ws;
  u16* qb16   = (u16*)(w + (0ull << 20));  // +QSZ: kb16, +2*QSZ: Vt
  u16* kb16   = (u16*)(w + (16ull << 20));
  u16* Vt     = (u16*)(w + (32ull << 20));
  u16* xb     = (u16*)(w + (48ull << 20));
  u16* part16 = (u16*)(w + (64ull << 20));
  u16* Wqkv   = (u16*)(w + (80ull << 20)); // 3072 x 1024 Bt (Wq|Wk|Wv)
  u16* Wot    = (u16*)(w + (86ull << 20));
  u16* W1b    = (u16*)(w + (88ull << 20));
  u16* W2b    = (u16*)(w + (96ull << 20));
  float* Lrcp = (float*)(w + (104ull << 20));
  u16* o1b = qb16;            // after attention
  u16* hc  = kb16;            // 64 MB [16,80M) after attention + Wo GEMM
  float* o1 = (float*)d_out;

  dim3 thr(256);

  // ---- convert weights/activations to bf16 (Bt layout = N x K) ----
  int n4x = (M_ * D_) / 4;
  cvt_k<<<dim3((n4x + 255) / 256), thr, 0, stream>>>(x, xb, n4x);
  tconv_k<<<dim3(2, 32, 16), thr, 0, stream>>>(Wq, Wqkv, 1024, 64);
  tconv_k<<<dim3(2, 32, 16), thr, 0, stream>>>(Wk, Wqkv + 1048576, 1024, 64);
  tconv_k<<<dim3(2, 32, 16), thr, 0, stream>>>(Wv, Wqkv + 2097152, 1024, 64);
  tconv_k<<<dim3(32, 32, 1), thr, 0, stream>>>(Wo, Wot, 1024, 1024);
  int n4w = (FF_ * D_) / 4;
  cvt_k<<<dim3((n4w + 255) / 256), thr, 0, stream>>>(W1, W1b, n4w);
  cvt_k<<<dim3((n4w + 255) / 256), thr, 0, stream>>>(W2, W2b, n4w);

  // ---- fused QKV projection (N=3072; epilogue splits Q/K row-major, V^T) --
  gemm16_k<6><<<dim3((3072 / 128) * (M_ / 128)), thr, 0, stream>>>(
      xb, Wqkv, M_, 3072, D_, D_, D_, 3072 / 128, nullptr, D_, qb16,
      nullptr, nullptr);

  // ---- attention (query-axis softmax, no-max two-pass, MFMA) ----
  dim3 ga(T_ / 128, H_, B_);
  attn_lsum_k<<<ga, thr, 0, stream>>>(qb16, kb16, Lrcp);
  vscale_k<<<dim3((int)(QSZ / 8 / 256)), thr, 0, stream>>>(Vt, Lrcp);
  attn_pv_k<<<ga, thr, 0, stream>>>(qb16, kb16, Vt, part16);

  // ---- out1 = part @ Wo + x -> d_out (fp32); pseudo-norm + bf16 copy ----
  gemm16_k<1><<<dim3((D_ / 128) * (M_ / 128)), thr, 0, stream>>>(
      part16, Wot, M_, D_, D_, D_, D_, D_ / 128, o1, D_, nullptr, x, nullptr);
  norm_k<true><<<dim3(M_), thr, 0, stream>>>(o1, o1, o1b);

  // ---- FF, unchunked: hc = relu(o1b @ W1^T + b1); out = hc @ W2^T + b2 + o1
  gemm16_k<2><<<dim3((FF_ / 128) * (M_ / 128)), thr, 0, stream>>>(
      o1b, W1b, M_, FF_, D_, D_, D_, FF_ / 128, nullptr, FF_, hc,
      nullptr, b1);
  gemm16_k<3><<<dim3((D_ / 128) * (M_ / 128)), thr, 0, stream>>>(
      hc, W2b, M_, D_, FF_, FF_, FF_, D_ / 128, o1, D_, nullptr, o1, b2);

  // ---- final pseudo-norm in place on d_out ----
  norm_k<false><<<dim3(M_), thr, 0, stream>>>(o1, o1, nullptr);
}